// Round 9
// baseline (484.338 us; speedup 1.0000x reference)
//
#include <hip/hip_runtime.h>
#include <cstdint>
#include <cstddef>

#define DEV static __device__ __forceinline__

typedef __bf16 bf16x8 __attribute__((ext_vector_type(8)));
typedef float f32x4 __attribute__((ext_vector_type(4)));
typedef unsigned short u16x8 __attribute__((ext_vector_type(8)));
typedef unsigned short u16;

DEV u16 f2bf(float f) { __bf16 b = (__bf16)f; return __builtin_bit_cast(u16, b); }

DEV void async_cp16(const void* g, void* l) {
    __builtin_amdgcn_global_load_lds(
        (const __attribute__((address_space(1))) void*)g,
        (__attribute__((address_space(3))) void*)l, 16, 0, 0);
}

DEV void wait_vm6() { asm volatile("s_waitcnt vmcnt(6)" ::: "memory"); }
DEV void wait_vm4() { asm volatile("s_waitcnt vmcnt(4)" ::: "memory"); }
DEV void wait_vm0() { asm volatile("s_waitcnt vmcnt(0)" ::: "memory"); }
DEV void wait_lgkm0() { asm volatile("s_waitcnt lgkmcnt(0)" ::: "memory"); }

// gelu with module's custom 0.04715 constant; overflow-safe tanh
DEV float gelu_fn(float x) {
    const float c = 0.7978845608028654f; // sqrt(2/pi)
    float t = c * (x + 0.04715f * x * x * x);
    float e = __expf(2.f * t);
    float th = 1.f - 2.f / (e + 1.f); // tanh(t), safe at +-inf
    return 0.5f * x * (1.f + th);
}

// ---------------- weight transpose + cast: W[K][N] f32 -> Wt[N][K] bf16 ----
__global__ __launch_bounds__(256) void wtrans_kernel(
    const float* __restrict__ W, u16* __restrict__ Wt, int K, int N)
{
    __shared__ float t[32][33];
    int n0 = blockIdx.x * 32, k0 = blockIdx.y * 32;
    int tx = threadIdx.x & 31, ty = threadIdx.x >> 5; // 32 x 8
#pragma unroll
    for (int i = 0; i < 4; ++i)
        t[ty + i * 8][tx] = W[(size_t)(k0 + ty + i * 8) * N + n0 + tx];
    __syncthreads();
#pragma unroll
    for (int i = 0; i < 4; ++i)
        Wt[(size_t)(n0 + ty + i * 8) * K + k0 + tx] = f2bf(t[tx][ty + i * 8]);
}

// ---------------- LayerNorm: f32 [rows][1024] -> bf16 ----------------------
__global__ __launch_bounds__(256) void ln_kernel(
    const float* __restrict__ X, const float* __restrict__ g,
    const float* __restrict__ sh, u16* __restrict__ Y)
{
    int row = blockIdx.x;
    const float4* xr = (const float4*)(X + (size_t)row * 1024);
    float4 x = xr[threadIdx.x];
    float s = x.x + x.y + x.z + x.w;
    float ss = x.x * x.x + x.y * x.y + x.z * x.z + x.w * x.w;
#pragma unroll
    for (int off = 32; off >= 1; off >>= 1) {
        s += __shfl_xor(s, off);
        ss += __shfl_xor(ss, off);
    }
    __shared__ float ps[4], pss[4];
    int wave = threadIdx.x >> 6, lane = threadIdx.x & 63;
    if (lane == 0) { ps[wave] = s; pss[wave] = ss; }
    __syncthreads();
    s = ps[0] + ps[1] + ps[2] + ps[3];
    ss = pss[0] + pss[1] + pss[2] + pss[3];
    float mean = s * (1.f / 1024.f);
    float var = ss * (1.f / 1024.f) - mean * mean;
    float rstd = rsqrtf(var + 1e-5f);
    int c = threadIdx.x * 4;
    ushort4 o;
    o.x = f2bf((x.x - mean) * rstd * g[c + 0] + sh[c + 0]);
    o.y = f2bf((x.y - mean) * rstd * g[c + 1] + sh[c + 1]);
    o.z = f2bf((x.z - mean) * rstd * g[c + 2] + sh[c + 2]);
    o.w = f2bf((x.w - mean) * rstd * g[c + 3] + sh[c + 3]);
    ((ushort4*)(Y + (size_t)row * 1024))[threadIdx.x] = o;
}

// ---------------- GEMM 128x128 (proven): C = A @ Bt^T ----------------------
// BK=32, 4 waves, 3-deep staging + counted vmcnt(4), single raw barrier per
// K-step (never drains the prefetch pipeline to 0 mid-loop).
template <int OUT_BF16, int HAS_BIAS, int HAS_RES, int ACT_GELU>
__global__ __launch_bounds__(256) void gemm_kernel(
    const u16* __restrict__ A, const u16* __restrict__ Bt,
    const float* __restrict__ bias, const float* __restrict__ res,
    void* __restrict__ Cout, int M, int N, int K)
{
    __shared__ u16 As[3][128 * 32];
    __shared__ u16 Bs[3][128 * 32];
    const int tid = threadIdx.x;
    const int lane = tid & 63, wave = tid >> 6;
    const int wm = wave >> 1, wn = wave & 1;
    const int l16 = lane & 15, lg = lane >> 4;
    const int rowBase = blockIdx.y * 128;
    const int colBase = blockIdx.x * 128;

    f32x4 acc[4][4];
#pragma unroll
    for (int m = 0; m < 4; ++m)
#pragma unroll
        for (int n = 0; n < 4; ++n) acc[m][n] = (f32x4){0.f, 0.f, 0.f, 0.f};

#define GSTAGE(SB, KT)                                                        \
    {                                                                         \
        _Pragma("unroll")                                                     \
        for (int i_ = 0; i_ < 2; ++i_) {                                      \
            int eo = tid * 8 + i_ * 2048;                                     \
            int r_ = eo >> 5, c_ = eo & 31;                                   \
            async_cp16(A + (size_t)(rowBase + r_) * K + (KT) + c_, As[SB] + eo); \
            async_cp16(Bt + (size_t)(colBase + r_) * K + (KT) + c_, Bs[SB] + eo); \
        }                                                                     \
    }

    const int nt = K >> 5;
    GSTAGE(0, 0);
    GSTAGE(1, 32);
    wait_vm4();
    __builtin_amdgcn_s_barrier();
    __builtin_amdgcn_sched_barrier(0);

    int cur = 0, stg = 2;
    for (int t = 0; t < nt; ++t) {
        const bool more = (t + 2 < nt);
        if (more) GSTAGE(stg, (t + 2) * 32);

        bf16x8 af[4], bfr[4];
#pragma unroll
        for (int m = 0; m < 4; ++m)
            af[m] = *(const bf16x8*)(As[cur] + (wm * 64 + m * 16 + l16) * 32 + lg * 8);
#pragma unroll
        for (int n = 0; n < 4; ++n)
            bfr[n] = *(const bf16x8*)(Bs[cur] + (wn * 64 + n * 16 + l16) * 32 + lg * 8);
#pragma unroll
        for (int m = 0; m < 4; ++m)
#pragma unroll
            for (int n = 0; n < 4; ++n)
                acc[m][n] = __builtin_amdgcn_mfma_f32_16x16x32_bf16(
                    af[m], bfr[n], acc[m][n], 0, 0, 0);

        if (more) wait_vm4(); else wait_vm0();
        __builtin_amdgcn_s_barrier();
        __builtin_amdgcn_sched_barrier(0);
        cur = (cur == 2) ? 0 : cur + 1;
        stg = (stg == 2) ? 0 : stg + 1;
    }
#undef GSTAGE

#pragma unroll
    for (int m = 0; m < 4; ++m) {
#pragma unroll
        for (int n = 0; n < 4; ++n) {
            int gr0 = rowBase + wm * 64 + m * 16 + lg * 4;
            int gc = colBase + wn * 64 + n * 16 + l16;
            float bv = HAS_BIAS ? bias[gc] : 0.f;
#pragma unroll
            for (int r = 0; r < 4; ++r) {
                float v = acc[m][n][r] + bv;
                if (ACT_GELU) v = gelu_fn(v);
                if (HAS_RES) v += res[(size_t)(gr0 + r) * N + gc];
                if (OUT_BF16)
                    ((u16*)Cout)[(size_t)(gr0 + r) * N + gc] = f2bf(v);
                else
                    ((float*)Cout)[(size_t)(gr0 + r) * N + gc] = v;
            }
        }
    }
}

// ---------------- GEMM 256x256, BK=64, 8 waves, 8-phase (R8-proven) --------
template <int OUT_BF16, int HAS_BIAS, int ACT_GELU>
__global__ __launch_bounds__(512, 2) void gemm8p_kernel(
    const u16* __restrict__ A, const u16* __restrict__ Bt,
    const float* __restrict__ bias, void* __restrict__ Cout,
    int M, int N, int K)
{
    __shared__ u16 As[2][256 * 64];
    __shared__ u16 Bs[2][256 * 64];
    const int tid = threadIdx.x;
    const int lane = tid & 63, wave = tid >> 6;
    const int wm = wave >> 2, wn = wave & 3;     // 2 x 4 wave grid
    const int l16 = lane & 15, lg = lane >> 4;

    const int gx = gridDim.x, gy = gridDim.y;
    const int nwg = gx * gy;
    const int orig = (int)blockIdx.y * gx + (int)blockIdx.x;
    const int work = (orig & 7) * (nwg >> 3) + (orig >> 3);
    const int colBase = (work / gy) * 256;
    const int rowBase = (work % gy) * 256;

    f32x4 acc[8][4];
#pragma unroll
    for (int m = 0; m < 8; ++m)
#pragma unroll
        for (int n = 0; n < 4; ++n) acc[m][n] = (f32x4){0.f, 0.f, 0.f, 0.f};

#define STRIP(SB, KT, S)                                                      \
    {                                                                         \
        int tl_ = tid & 255, hf_ = tid >> 8;                                  \
        int r_ = hf_ * 128 + (S) * 32 + (tl_ >> 3);                           \
        int gl_ = (tl_ & 7) ^ (r_ & 7);                                       \
        int dst_ = r_ * 64 + (tl_ & 7) * 8;                                   \
        async_cp16(A + (size_t)(rowBase + r_) * K + (KT) + gl_ * 8, As[SB] + dst_); \
        async_cp16(Bt + (size_t)(colBase + r_) * K + (KT) + gl_ * 8, Bs[SB] + dst_); \
    }
#define FRAG_OFF(row, G) ((row) * 64 + (((G) ^ ((row) & 7)) * 8))

#define PHASE(BUF, QUAD, LOADB, STAGE, WAITN)                                 \
    {                                                                         \
        __builtin_amdgcn_sched_barrier(0);                                    \
        if (LOADB) {                                                          \
            _Pragma("unroll")                                                 \
            for (int nf = 0; nf < 4; ++nf) {                                  \
                int row = wn * 64 + nf * 16 + l16;                            \
                _Pragma("unroll")                                             \
                for (int ks = 0; ks < 2; ++ks)                                \
                    bfr[nf][ks] = *(const bf16x8*)(Bs[BUF] + FRAG_OFF(row, lg + ks * 4)); \
            }                                                                 \
        }                                                                     \
        bf16x8 af[2][2];                                                      \
        _Pragma("unroll")                                                     \
        for (int mi = 0; mi < 2; ++mi) {                                      \
            int row = wm * 128 + (QUAD) * 32 + mi * 16 + l16;                 \
            _Pragma("unroll")                                                 \
            for (int ks = 0; ks < 2; ++ks)                                    \
                af[mi][ks] = *(const bf16x8*)(As[BUF] + FRAG_OFF(row, lg + ks * 4)); \
        }                                                                     \
        STAGE;                                                                \
        __builtin_amdgcn_sched_barrier(0);                                    \
        __builtin_amdgcn_s_barrier();                                         \
        __builtin_amdgcn_s_setprio(1);                                        \
        _Pragma("unroll")                                                     \
        for (int mi = 0; mi < 2; ++mi)                                        \
            _Pragma("unroll")                                                 \
            for (int nf = 0; nf < 4; ++nf)                                    \
                _Pragma("unroll")                                             \
                for (int ks = 0; ks < 2; ++ks)                                \
                    acc[(QUAD) * 2 + mi][nf] =                                \
                        __builtin_amdgcn_mfma_f32_16x16x32_bf16(              \
                            af[mi][ks], bfr[nf][ks], acc[(QUAD) * 2 + mi][nf], 0, 0, 0); \
        __builtin_amdgcn_s_setprio(0);                                        \
        __builtin_amdgcn_sched_barrier(0);                                    \
        WAITN;                                                                \
        __builtin_amdgcn_s_barrier();                                         \
    }

    const int nt = K >> 6;
    const int half = nt >> 1;

    STRIP(0, 0, 0); STRIP(0, 0, 1); STRIP(0, 0, 2); STRIP(0, 0, 3);
    STRIP(1, 64, 0); STRIP(1, 64, 1); STRIP(1, 64, 2);
    wait_vm6();
    __builtin_amdgcn_s_barrier();
    __builtin_amdgcn_sched_barrier(0);

    for (int it = 0; it < half; ++it) {
        const int kt1 = (it * 2 + 1) << 6;
        const int kt2 = (it * 2 + 2) << 6;
        const int kt3 = (it * 2 + 3) << 6;
        const bool more = (it + 1 < half);
        bf16x8 bfr[4][2];
        PHASE(0, 0, 1, STRIP(1, kt1, 3), ((void)0));
        PHASE(0, 1, 0, if (more) STRIP(0, kt2, 0), ((void)0));
        PHASE(0, 2, 0, if (more) STRIP(0, kt2, 1), ((void)0));
        PHASE(0, 3, 0, if (more) STRIP(0, kt2, 2),
              if (more) wait_vm6(); else wait_vm0());
        PHASE(1, 0, 1, if (more) STRIP(0, kt2, 3), ((void)0));
        PHASE(1, 1, 0, if (more) STRIP(1, kt3, 0), ((void)0));
        PHASE(1, 2, 0, if (more) STRIP(1, kt3, 1), ((void)0));
        PHASE(1, 3, 0, if (more) STRIP(1, kt3, 2),
              if (more) wait_vm6(); else wait_vm0());
    }
#undef STRIP
#undef FRAG_OFF
#undef PHASE

#pragma unroll
    for (int mf = 0; mf < 8; ++mf) {
#pragma unroll
        for (int nf = 0; nf < 4; ++nf) {
            int gr0 = rowBase + wm * 128 + mf * 16 + lg * 4;
            int gc = colBase + wn * 64 + nf * 16 + l16;
            float bv = HAS_BIAS ? bias[gc] : 0.f;
#pragma unroll
            for (int r = 0; r < 4; ++r) {
                float v = acc[mf][nf][r] + bv;
                if (ACT_GELU) v = gelu_fn(v);
                if (OUT_BF16)
                    ((u16*)Cout)[(size_t)(gr0 + r) * N + gc] = f2bf(v);
                else
                    ((float*)Cout)[(size_t)(gr0 + r) * N + gc] = v;
            }
        }
    }
}

// ---------------- causal flash attention (v7: 2-ahead pipeline) ------------
// QKV fused: bf16 [8192][3072]. Z: bf16 [8192][1024].
// 4 waves, QBLK=128, KVBLK=64. K staged TWO chunks ahead (3 LDS bufs); V
// loaded two ahead into ping-pong regs, written one ahead. WRITE_V's implicit
// register-dep vmcnt (==vmcnt(6)) drains exactly chunk kc+1's K+V (issued a
// full iteration earlier -> latency covered); K(kc+2)/V(kc+2) stay in flight.
// Loop barrier = lgkmcnt(0) + raw s_barrier (no vmcnt(0) drain anywhere).
// Max-free softmax (|S|<=6 by construction).
__global__ __launch_bounds__(256) void attn_kernel(
    const u16* __restrict__ QKV, u16* __restrict__ Z)
{
    __shared__ u16 Ks[3][64 * 64];
    __shared__ u16 Vt[2][64 * 64];
    __shared__ u16 Pl[4][32 * 64];

    const int bh = blockIdx.y;
    const int b = bh >> 4, h = bh & 15;
    const int qt = (int)gridDim.x - 1 - (int)blockIdx.x;  // heavy tiles first
    const int tid = threadIdx.x;
    const int wave = tid >> 6, lane = tid & 63;
    const int l16 = lane & 15, lg = lane >> 4;

    const size_t baseQ = (size_t)b * 2048 * 3072 + (size_t)h * 64;
    const size_t baseK = baseQ + 1024;
    const size_t baseV = baseQ + 2048;

    const int q0w = qt * 128 + wave * 32;

    // Q fragments, pre-scaled by 1/sqrt(64)=0.125 (exact pow2)
    bf16x8 aq[2][2];
#pragma unroll
    for (int mq = 0; mq < 2; ++mq) {
        const u16* qp = QKV + baseQ + (size_t)(q0w + mq * 16 + l16) * 3072;
#pragma unroll
        for (int hf = 0; hf < 2; ++hf) {
            bf16x8 v = *(const bf16x8*)(qp + hf * 32 + lg * 8);
#pragma unroll
            for (int j = 0; j < 8; ++j) v[j] = (__bf16)((float)v[j] * 0.125f);
            aq[mq][hf] = v;
        }
    }

    f32x4 o[2][4];
    float lrow[2][4];
#pragma unroll
    for (int mq = 0; mq < 2; ++mq)
#pragma unroll
        for (int i = 0; i < 4; ++i) {
            o[mq][i] = (f32x4){0.f, 0.f, 0.f, 0.f};
            lrow[mq][i] = 0.f;
        }

    const int nch = 2 * qt + 2;

#define STAGE_K(BUF, KB)                                                      \
    {                                                                         \
        _Pragma("unroll")                                                     \
        for (int i = 0; i < 2; ++i) {                                         \
            int n = tid + i * 256;                                            \
            int r = n >> 3;                                                   \
            int lb = ((n & 7) * 16) ^ ((r & 7) << 4);                         \
            async_cp16(QKV + baseK + (size_t)((KB) + r) * 3072 + (lb >> 1),   \
                       Ks[BUF] + n * 8);                                      \
        }                                                                     \
    }
#define LOAD_V(KB, V0, V1)                                                    \
    {                                                                         \
        const u16* vp = QKV + baseV + (size_t)((KB) + lane) * 3072;           \
        V0 = *(const u16x8*)(vp + wave * 8);                                  \
        V1 = *(const u16x8*)(vp + wave * 8 + 32);                             \
    }
#define WRITE_V(BUF, V0, V1)                                                  \
    {                                                                         \
        _Pragma("unroll")                                                     \
        for (int j = 0; j < 8; ++j) {                                         \
            int d0 = wave * 8 + j;                                            \
            int by0 = (d0 * 128 + lane * 2) ^ ((d0 & 7) << 4);                \
            Vt[BUF][by0 >> 1] = V0[j];                                        \
            int d1 = d0 + 32;                                                 \
            int by1 = (d1 * 128 + lane * 2) ^ ((d1 & 7) << 4);                \
            Vt[BUF][by1 >> 1] = V1[j];                                        \
        }                                                                     \
    }
#define SOFTMAX_BODY(DIAG)                                                    \
    _Pragma("unroll")                                                         \
    for (int mq = 0; mq < 2; ++mq) {                                          \
        _Pragma("unroll")                                                     \
        for (int r = 0; r < 4; ++r) {                                         \
            float sv0 = s[mq][0][r];                                          \
            float sv1 = s[mq][1][r];                                          \
            float sv2 = s[mq][2][r];                                          \
            float sv3 = s[mq][3][r];                                          \
            if (DIAG) {                                                       \
                const int q = q0w + mq * 16 + lg * 4 + r;                     \
                if (kbase + 0 + l16 > q)  sv0 = -1e30f;                       \
                if (kbase + 16 + l16 > q) sv1 = -1e30f;                       \
                if (kbase + 32 + l16 > q) sv2 = -1e30f;                       \
                if (kbase + 48 + l16 > q) sv3 = -1e30f;                       \
            }                                                                 \
            float p0 = __expf(sv0), p1 = __expf(sv1);                         \
            float p2 = __expf(sv2), p3 = __expf(sv3);                         \
            lrow[mq][r] += (p0 + p1) + (p2 + p3);                             \
            int rowm = mq * 16 + lg * 4 + r;                                  \
            int rb = rowm * 128, swz = (rowm & 7) << 4;                       \
            Pl[wave][(rb + ((0  + 2 * l16) ^ swz)) >> 1] = f2bf(p0);          \
            Pl[wave][(rb + ((32 + 2 * l16) ^ swz)) >> 1] = f2bf(p1);          \
            Pl[wave][(rb + ((64 + 2 * l16) ^ swz)) >> 1] = f2bf(p2);          \
            Pl[wave][(rb + ((96 + 2 * l16) ^ swz)) >> 1] = f2bf(p3);          \
        }                                                                     \
    }

    // ---- prologue: K0,K1 staged; V0 written; V1 in regs ----
    u16x8 vA0, vA1, vB0, vB1;
    STAGE_K(0, 0);
    {
        u16x8 v0, v1;
        LOAD_V(0, v0, v1);
        WRITE_V(0, v0, v1);          // implicit vmcnt wait drains K0 (older) too
    }
    if (nch > 1) {
        STAGE_K(1, 64);
        LOAD_V(64, vA0, vA1);
    }
    wait_lgkm0();
    __builtin_amdgcn_s_barrier();
    __builtin_amdgcn_sched_barrier(0);

    int kcur = 0;
    for (int kc = 0; kc < nch; ++kc) {
        const int kbase = kc * 64;
        const bool m1 = (kc + 1 < nch);
        const bool m2 = (kc + 2 < nch);
        if (m2) {
            int kstg = (kcur == 0) ? 2 : kcur - 1;   // (kcur+2)%3
            STAGE_K(kstg, kbase + 128);
            LOAD_V(kbase + 128, vB0, vB1);
        }

        if (q0w + 31 >= kbase) {
            // ---- QK^T: S[32 q][64 k] ----
            f32x4 s[2][4];
#pragma unroll
            for (int mq = 0; mq < 2; ++mq)
#pragma unroll
                for (int t = 0; t < 4; ++t) s[mq][t] = (f32x4){0.f, 0.f, 0.f, 0.f};
            __builtin_amdgcn_s_setprio(1);
#pragma unroll
            for (int t = 0; t < 4; ++t) {
                int row = t * 16 + l16;
                int swz = (row & 7) << 4;
                bf16x8 bk0 = *(const bf16x8*)(Ks[kcur] + ((row * 128 + ((16 * lg) ^ swz)) >> 1));
                bf16x8 bk1 = *(const bf16x8*)(Ks[kcur] + ((row * 128 + ((64 + 16 * lg) ^ swz)) >> 1));
#pragma unroll
                for (int mq = 0; mq < 2; ++mq) {
                    s[mq][t] = __builtin_amdgcn_mfma_f32_16x16x32_bf16(aq[mq][0], bk0, s[mq][t], 0, 0, 0);
                    s[mq][t] = __builtin_amdgcn_mfma_f32_16x16x32_bf16(aq[mq][1], bk1, s[mq][t], 0, 0, 0);
                }
            }
            __builtin_amdgcn_s_setprio(0);

            // ---- max-free softmax + P -> LDS ----
            const bool diag = (kbase + 63 > q0w);
            if (diag) { SOFTMAX_BODY(1) } else { SOFTMAX_BODY(0) }

            // ---- PV: O[32 q][64 d] += P @ V ----
            bf16x8 bv[2][4];
#pragma unroll
            for (int kst = 0; kst < 2; ++kst)
#pragma unroll
                for (int ct = 0; ct < 4; ++ct) {
                    int d = ct * 16 + l16;
                    bv[kst][ct] = *(const bf16x8*)(Vt[kc & 1] + ((d * 128 + ((64 * kst + 16 * lg) ^ ((d & 7) << 4))) >> 1));
                }
            __builtin_amdgcn_s_setprio(1);
#pragma unroll
            for (int mq = 0; mq < 2; ++mq) {
                int rowm = mq * 16 + l16;
                int swz = (rowm & 7) << 4;
                bf16x8 ap0 = *(const bf16x8*)(&Pl[wave][(rowm * 128 + ((16 * lg) ^ swz)) >> 1]);
                bf16x8 ap1 = *(const bf16x8*)(&Pl[wave][(rowm * 128 + ((64 + 16 * lg) ^ swz)) >> 1]);
#pragma unroll
                for (int ct = 0; ct < 4; ++ct) {
                    o[mq][ct] = __builtin_amdgcn_mfma_f32_16x16x32_bf16(ap0, bv[0][ct], o[mq][ct], 0, 0, 0);
                    o[mq][ct] = __builtin_amdgcn_mfma_f32_16x16x32_bf16(ap1, bv[1][ct], o[mq][ct], 0, 0, 0);
                }
            }
            __builtin_amdgcn_s_setprio(0);
        }

        // write-late V(kc+1): implicit vmcnt wait == vmcnt(6) here, draining
        // exactly K(kc+1)+V(kc+1) (issued last iteration); K/V(kc+2) in flight.
        if (m1) { WRITE_V((kc + 1) & 1, vA0, vA1); }
        wait_lgkm0();
        __builtin_amdgcn_s_barrier();
        __builtin_amdgcn_sched_barrier(0);
        vA0 = vB0; vA1 = vB1;
        kcur = (kcur == 2) ? 0 : kcur + 1;
    }

    // ---- epilogue: reduce l across the 16 k-lanes, normalize, store ----
#pragma unroll
    for (int mq = 0; mq < 2; ++mq)
#pragma unroll
        for (int r = 0; r < 4; ++r) {
            float l = lrow[mq][r];
            l += __shfl_xor(l, 1);
            l += __shfl_xor(l, 2);
            l += __shfl_xor(l, 4);
            l += __shfl_xor(l, 8);
            float inv = 1.f / l;
            size_t zr = ((size_t)b * 2048 + q0w + mq * 16 + lg * 4 + r) * 1024 + h * 64;
#pragma unroll
            for (int ct = 0; ct < 4; ++ct)
                Z[zr + ct * 16 + l16] = f2bf(o[mq][ct][r] * inv);
        }
#undef STAGE_K
#undef LOAD_V
#undef WRITE_V
#undef SOFTMAX_BODY
}

// ---------------------------------------------------------------------------
extern "C" void kernel_launch(void* const* d_in, const int* in_sizes, int n_in,
                              void* d_out, int out_size, void* d_ws, size_t ws_size,
                              hipStream_t stream)
{
    const float* X  = (const float*)d_in[0];
    const float* Wq = (const float*)d_in[1];
    const float* Wk = (const float*)d_in[2];
    const float* Wv = (const float*)d_in[3];
    const float* Wo = (const float*)d_in[4];
    const float* bo = (const float*)d_in[5];
    const float* W1 = (const float*)d_in[6];
    const float* b1 = (const float*)d_in[7];
    const float* W2 = (const float*)d_in[8];
    const float* b2 = (const float*)d_in[9];
    const float* g1 = (const float*)d_in[10];
    const float* s1 = (const float*)d_in[11];
    const float* g2 = (const float*)d_in[12];
    const float* s2 = (const float*)d_in[13];
    float* out = (float*)d_out;

    uint8_t* ws = (uint8_t*)d_ws;
    const size_t MB = 1024 * 1024;
    u16* Wqkvt = (u16*)(ws + 0 * MB);   // [3072][1024] bf16 (Q,K,V stacked)
    u16* Wot   = (u16*)(ws + 6 * MB);   // [1024][1024]
    u16* W1t   = (u16*)(ws + 8 * MB);   // [4096][1024]
    u16* W2t   = (u16*)(ws + 16 * MB);  // [1024][4096]
    u16* Yb    = (u16*)(ws + 24 * MB);  // [8192][1024] LN1 out
    u16* QKVb  = (u16*)(ws + 40 * MB);  // [8192][3072]
    u16* Zb    = (u16*)(ws + 24 * MB);  // reuse Yb (dead after QKV gemm)
    u16* Y2b   = (u16*)(ws + 40 * MB);  // reuse QKVb (dead after attention)
    u16* Hb    = (u16*)(ws + 56 * MB);  // [8192][4096]

    // 1) weight prep
    wtrans_kernel<<<dim3(32, 32), 256, 0, stream>>>(Wq, Wqkvt, 1024, 1024);
    wtrans_kernel<<<dim3(32, 32), 256, 0, stream>>>(Wk, Wqkvt + 1024 * 1024, 1024, 1024);
    wtrans_kernel<<<dim3(32, 32), 256, 0, stream>>>(Wv, Wqkvt + 2048 * 1024, 1024, 1024);
    wtrans_kernel<<<dim3(32, 32), 256, 0, stream>>>(Wo, Wot, 1024, 1024);
    wtrans_kernel<<<dim3(128, 32), 256, 0, stream>>>(W1, W1t, 1024, 4096);
    wtrans_kernel<<<dim3(32, 128), 256, 0, stream>>>(W2, W2t, 4096, 1024);

    // 2) LN1
    ln_kernel<<<8192, 256, 0, stream>>>(X, g1, s1, Yb);

    // 3) fused QKV projection (128^2 kernel; 1536 blocks, balanced)
    gemm_kernel<1, 0, 0, 0><<<dim3(24, 64), 256, 0, stream>>>(Yb, Wqkvt, nullptr, nullptr, QKVb, 8192, 3072, 1024);

    // 4) attention (2-ahead pipelined)
    attn_kernel<<<dim3(16, 64), 256, 0, stream>>>(QKVb, Zb);

    // 5) Wo projection + bo + shortcut X -> X1 (fp32 in d_out)
    gemm_kernel<0, 1, 1, 0><<<dim3(8, 64), 256, 0, stream>>>(Zb, Wot, bo, X, out, 8192, 1024, 1024);

    // 6) LN2
    ln_kernel<<<8192, 256, 0, stream>>>(out, g2, s2, Y2b);

    // 7) FFN up + gelu (8-phase 256^2; grid 16x32 = 512 % 8 == 0, balanced)
    gemm8p_kernel<1, 1, 1><<<dim3(16, 32), 512, 0, stream>>>(Y2b, W1t, b1, Hb, 8192, 4096, 1024);

    // 8) FFN down + b2 + residual (in-place on d_out, element-wise safe)
    gemm_kernel<0, 1, 1, 0><<<dim3(8, 64), 256, 0, stream>>>(Hb, W2t, b2, out, out, 8192, 1024, 4096);
}

// Round 10
// 475.451 us; speedup vs baseline: 1.0187x; 1.0187x over previous
//
#include <hip/hip_runtime.h>
#include <cstdint>
#include <cstddef>

#define DEV static __device__ __forceinline__

typedef __bf16 bf16x8 __attribute__((ext_vector_type(8)));
typedef float f32x4 __attribute__((ext_vector_type(4)));
typedef unsigned short u16x8 __attribute__((ext_vector_type(8)));
typedef unsigned short u16x4 __attribute__((ext_vector_type(4)));
typedef short s16x4 __attribute__((ext_vector_type(4)));
typedef unsigned short u16;

DEV u16 f2bf(float f) { __bf16 b = (__bf16)f; return __builtin_bit_cast(u16, b); }

DEV void async_cp16(const void* g, void* l) {
    __builtin_amdgcn_global_load_lds(
        (const __attribute__((address_space(1))) void*)g,
        (__attribute__((address_space(3))) void*)l, 16, 0, 0);
}

DEV void wait_vm6() { asm volatile("s_waitcnt vmcnt(6)" ::: "memory"); }
DEV void wait_vm4() { asm volatile("s_waitcnt vmcnt(4)" ::: "memory"); }
DEV void wait_vm0() { asm volatile("s_waitcnt vmcnt(0)" ::: "memory"); }

// gelu with module's custom 0.04715 constant; overflow-safe tanh
DEV float gelu_fn(float x) {
    const float c = 0.7978845608028654f; // sqrt(2/pi)
    float t = c * (x + 0.04715f * x * x * x);
    float e = __expf(2.f * t);
    float th = 1.f - 2.f / (e + 1.f); // tanh(t), safe at +-inf
    return 0.5f * x * (1.f + th);
}

// ---------------- weight transpose + cast: W[K][N] f32 -> Wt[N][K] bf16 ----
__global__ __launch_bounds__(256) void wtrans_kernel(
    const float* __restrict__ W, u16* __restrict__ Wt, int K, int N)
{
    __shared__ float t[32][33];
    int n0 = blockIdx.x * 32, k0 = blockIdx.y * 32;
    int tx = threadIdx.x & 31, ty = threadIdx.x >> 5; // 32 x 8
#pragma unroll
    for (int i = 0; i < 4; ++i)
        t[ty + i * 8][tx] = W[(size_t)(k0 + ty + i * 8) * N + n0 + tx];
    __syncthreads();
#pragma unroll
    for (int i = 0; i < 4; ++i)
        Wt[(size_t)(n0 + ty + i * 8) * K + k0 + tx] = f2bf(t[tx][ty + i * 8]);
}

// ---------------- LayerNorm: f32 [rows][1024] -> bf16 ----------------------
__global__ __launch_bounds__(256) void ln_kernel(
    const float* __restrict__ X, const float* __restrict__ g,
    const float* __restrict__ sh, u16* __restrict__ Y)
{
    int row = blockIdx.x;
    const float4* xr = (const float4*)(X + (size_t)row * 1024);
    float4 x = xr[threadIdx.x];
    float s = x.x + x.y + x.z + x.w;
    float ss = x.x * x.x + x.y * x.y + x.z * x.z + x.w * x.w;
#pragma unroll
    for (int off = 32; off >= 1; off >>= 1) {
        s += __shfl_xor(s, off);
        ss += __shfl_xor(ss, off);
    }
    __shared__ float ps[4], pss[4];
    int wave = threadIdx.x >> 6, lane = threadIdx.x & 63;
    if (lane == 0) { ps[wave] = s; pss[wave] = ss; }
    __syncthreads();
    s = ps[0] + ps[1] + ps[2] + ps[3];
    ss = pss[0] + pss[1] + pss[2] + pss[3];
    float mean = s * (1.f / 1024.f);
    float var = ss * (1.f / 1024.f) - mean * mean;
    float rstd = rsqrtf(var + 1e-5f);
    int c = threadIdx.x * 4;
    ushort4 o;
    o.x = f2bf((x.x - mean) * rstd * g[c + 0] + sh[c + 0]);
    o.y = f2bf((x.y - mean) * rstd * g[c + 1] + sh[c + 1]);
    o.z = f2bf((x.z - mean) * rstd * g[c + 2] + sh[c + 2]);
    o.w = f2bf((x.w - mean) * rstd * g[c + 3] + sh[c + 3]);
    ((ushort4*)(Y + (size_t)row * 1024))[threadIdx.x] = o;
}

// ---------------- GEMM 128x128 (proven): C = A @ Bt^T ----------------------
// BK=32, 4 waves, 3-deep staging + counted vmcnt(4), single raw barrier per
// K-step (never drains the prefetch pipeline to 0 mid-loop).
template <int OUT_BF16, int HAS_BIAS, int HAS_RES, int ACT_GELU>
__global__ __launch_bounds__(256) void gemm_kernel(
    const u16* __restrict__ A, const u16* __restrict__ Bt,
    const float* __restrict__ bias, const float* __restrict__ res,
    void* __restrict__ Cout, int M, int N, int K)
{
    __shared__ u16 As[3][128 * 32];
    __shared__ u16 Bs[3][128 * 32];
    const int tid = threadIdx.x;
    const int lane = tid & 63, wave = tid >> 6;
    const int wm = wave >> 1, wn = wave & 1;
    const int l16 = lane & 15, lg = lane >> 4;
    const int rowBase = blockIdx.y * 128;
    const int colBase = blockIdx.x * 128;

    f32x4 acc[4][4];
#pragma unroll
    for (int m = 0; m < 4; ++m)
#pragma unroll
        for (int n = 0; n < 4; ++n) acc[m][n] = (f32x4){0.f, 0.f, 0.f, 0.f};

#define GSTAGE(SB, KT)                                                        \
    {                                                                         \
        _Pragma("unroll")                                                     \
        for (int i_ = 0; i_ < 2; ++i_) {                                      \
            int eo = tid * 8 + i_ * 2048;                                     \
            int r_ = eo >> 5, c_ = eo & 31;                                   \
            async_cp16(A + (size_t)(rowBase + r_) * K + (KT) + c_, As[SB] + eo); \
            async_cp16(Bt + (size_t)(colBase + r_) * K + (KT) + c_, Bs[SB] + eo); \
        }                                                                     \
    }

    const int nt = K >> 5;
    GSTAGE(0, 0);
    GSTAGE(1, 32);
    wait_vm4();
    __builtin_amdgcn_s_barrier();
    __builtin_amdgcn_sched_barrier(0);

    int cur = 0, stg = 2;
    for (int t = 0; t < nt; ++t) {
        const bool more = (t + 2 < nt);
        if (more) GSTAGE(stg, (t + 2) * 32);

        bf16x8 af[4], bfr[4];
#pragma unroll
        for (int m = 0; m < 4; ++m)
            af[m] = *(const bf16x8*)(As[cur] + (wm * 64 + m * 16 + l16) * 32 + lg * 8);
#pragma unroll
        for (int n = 0; n < 4; ++n)
            bfr[n] = *(const bf16x8*)(Bs[cur] + (wn * 64 + n * 16 + l16) * 32 + lg * 8);
#pragma unroll
        for (int m = 0; m < 4; ++m)
#pragma unroll
            for (int n = 0; n < 4; ++n)
                acc[m][n] = __builtin_amdgcn_mfma_f32_16x16x32_bf16(
                    af[m], bfr[n], acc[m][n], 0, 0, 0);

        if (more) wait_vm4(); else wait_vm0();
        __builtin_amdgcn_s_barrier();
        __builtin_amdgcn_sched_barrier(0);
        cur = (cur == 2) ? 0 : cur + 1;
        stg = (stg == 2) ? 0 : stg + 1;
    }
#undef GSTAGE

#pragma unroll
    for (int m = 0; m < 4; ++m) {
#pragma unroll
        for (int n = 0; n < 4; ++n) {
            int gr0 = rowBase + wm * 64 + m * 16 + lg * 4;
            int gc = colBase + wn * 64 + n * 16 + l16;
            float bv = HAS_BIAS ? bias[gc] : 0.f;
#pragma unroll
            for (int r = 0; r < 4; ++r) {
                float v = acc[m][n][r] + bv;
                if (ACT_GELU) v = gelu_fn(v);
                if (HAS_RES) v += res[(size_t)(gr0 + r) * N + gc];
                if (OUT_BF16)
                    ((u16*)Cout)[(size_t)(gr0 + r) * N + gc] = f2bf(v);
                else
                    ((float*)Cout)[(size_t)(gr0 + r) * N + gc] = v;
            }
        }
    }
}

// ---------------- GEMM 256x256, BK=64, 8 waves, 8-phase (R8-proven) --------
template <int OUT_BF16, int HAS_BIAS, int ACT_GELU>
__global__ __launch_bounds__(512, 2) void gemm8p_kernel(
    const u16* __restrict__ A, const u16* __restrict__ Bt,
    const float* __restrict__ bias, void* __restrict__ Cout,
    int M, int N, int K)
{
    __shared__ u16 As[2][256 * 64];
    __shared__ u16 Bs[2][256 * 64];
    const int tid = threadIdx.x;
    const int lane = tid & 63, wave = tid >> 6;
    const int wm = wave >> 2, wn = wave & 3;     // 2 x 4 wave grid
    const int l16 = lane & 15, lg = lane >> 4;

    const int gx = gridDim.x, gy = gridDim.y;
    const int nwg = gx * gy;
    const int orig = (int)blockIdx.y * gx + (int)blockIdx.x;
    const int work = (orig & 7) * (nwg >> 3) + (orig >> 3);
    const int colBase = (work / gy) * 256;
    const int rowBase = (work % gy) * 256;

    f32x4 acc[8][4];
#pragma unroll
    for (int m = 0; m < 8; ++m)
#pragma unroll
        for (int n = 0; n < 4; ++n) acc[m][n] = (f32x4){0.f, 0.f, 0.f, 0.f};

#define STRIP(SB, KT, S)                                                      \
    {                                                                         \
        int tl_ = tid & 255, hf_ = tid >> 8;                                  \
        int r_ = hf_ * 128 + (S) * 32 + (tl_ >> 3);                           \
        int gl_ = (tl_ & 7) ^ (r_ & 7);                                       \
        int dst_ = r_ * 64 + (tl_ & 7) * 8;                                   \
        async_cp16(A + (size_t)(rowBase + r_) * K + (KT) + gl_ * 8, As[SB] + dst_); \
        async_cp16(Bt + (size_t)(colBase + r_) * K + (KT) + gl_ * 8, Bs[SB] + dst_); \
    }
#define FRAG_OFF(row, G) ((row) * 64 + (((G) ^ ((row) & 7)) * 8))

#define PHASE(BUF, QUAD, LOADB, STAGE, WAITN)                                 \
    {                                                                         \
        __builtin_amdgcn_sched_barrier(0);                                    \
        if (LOADB) {                                                          \
            _Pragma("unroll")                                                 \
            for (int nf = 0; nf < 4; ++nf) {                                  \
                int row = wn * 64 + nf * 16 + l16;                            \
                _Pragma("unroll")                                             \
                for (int ks = 0; ks < 2; ++ks)                                \
                    bfr[nf][ks] = *(const bf16x8*)(Bs[BUF] + FRAG_OFF(row, lg + ks * 4)); \
            }                                                                 \
        }                                                                     \
        bf16x8 af[2][2];                                                      \
        _Pragma("unroll")                                                     \
        for (int mi = 0; mi < 2; ++mi) {                                      \
            int row = wm * 128 + (QUAD) * 32 + mi * 16 + l16;                 \
            _Pragma("unroll")                                                 \
            for (int ks = 0; ks < 2; ++ks)                                    \
                af[mi][ks] = *(const bf16x8*)(As[BUF] + FRAG_OFF(row, lg + ks * 4)); \
        }                                                                     \
        STAGE;                                                                \
        __builtin_amdgcn_sched_barrier(0);                                    \
        __builtin_amdgcn_s_barrier();                                         \
        __builtin_amdgcn_s_setprio(1);                                        \
        _Pragma("unroll")                                                     \
        for (int mi = 0; mi < 2; ++mi)                                        \
            _Pragma("unroll")                                                 \
            for (int nf = 0; nf < 4; ++nf)                                    \
                _Pragma("unroll")                                             \
                for (int ks = 0; ks < 2; ++ks)                                \
                    acc[(QUAD) * 2 + mi][nf] =                                \
                        __builtin_amdgcn_mfma_f32_16x16x32_bf16(              \
                            af[mi][ks], bfr[nf][ks], acc[(QUAD) * 2 + mi][nf], 0, 0, 0); \
        __builtin_amdgcn_s_setprio(0);                                        \
        __builtin_amdgcn_sched_barrier(0);                                    \
        WAITN;                                                                \
        __builtin_amdgcn_s_barrier();                                         \
    }

    const int nt = K >> 6;
    const int half = nt >> 1;

    STRIP(0, 0, 0); STRIP(0, 0, 1); STRIP(0, 0, 2); STRIP(0, 0, 3);
    STRIP(1, 64, 0); STRIP(1, 64, 1); STRIP(1, 64, 2);
    wait_vm6();
    __builtin_amdgcn_s_barrier();
    __builtin_amdgcn_sched_barrier(0);

    for (int it = 0; it < half; ++it) {
        const int kt1 = (it * 2 + 1) << 6;
        const int kt2 = (it * 2 + 2) << 6;
        const int kt3 = (it * 2 + 3) << 6;
        const bool more = (it + 1 < half);
        bf16x8 bfr[4][2];
        PHASE(0, 0, 1, STRIP(1, kt1, 3), ((void)0));
        PHASE(0, 1, 0, if (more) STRIP(0, kt2, 0), ((void)0));
        PHASE(0, 2, 0, if (more) STRIP(0, kt2, 1), ((void)0));
        PHASE(0, 3, 0, if (more) STRIP(0, kt2, 2),
              if (more) wait_vm6(); else wait_vm0());
        PHASE(1, 0, 1, if (more) STRIP(0, kt2, 3), ((void)0));
        PHASE(1, 1, 0, if (more) STRIP(1, kt3, 0), ((void)0));
        PHASE(1, 2, 0, if (more) STRIP(1, kt3, 1), ((void)0));
        PHASE(1, 3, 0, if (more) STRIP(1, kt3, 2),
              if (more) wait_vm6(); else wait_vm0());
    }
#undef STRIP
#undef FRAG_OFF
#undef PHASE

#pragma unroll
    for (int mf = 0; mf < 8; ++mf) {
#pragma unroll
        for (int nf = 0; nf < 4; ++nf) {
            int gr0 = rowBase + wm * 128 + mf * 16 + lg * 4;
            int gc = colBase + wn * 64 + nf * 16 + l16;
            float bv = HAS_BIAS ? bias[gc] : 0.f;
#pragma unroll
            for (int r = 0; r < 4; ++r) {
                float v = acc[mf][nf][r] + bv;
                if (ACT_GELU) v = gelu_fn(v);
                if (OUT_BF16)
                    ((u16*)Cout)[(size_t)(gr0 + r) * N + gc] = f2bf(v);
                else
                    ((float*)Cout)[(size_t)(gr0 + r) * N + gc] = v;
            }
        }
    }
}

// ---------------- causal flash attention (v8: swapped QK^T, no P-LDS) ------
// QKV fused: bf16 [8192][3072]. Z: bf16 [8192][1024].
// 4 waves, QBLK=128, KVBLK=64, R6-proven double-buffer staging/barriers.
// QK^T computed SWAPPED: s = mfma(A=K-frag, B=Q-frag) -> S^T with q = l16
// fixed per lane, k = kbase+16t+4lg+r. The lane's 4 exp'd P values per
// k16-tile ARE the A-fragment of mfma_f32_16x16x16bf16_1k (row=l16, k=lg*4+j)
// -> PV needs no P shuffle / no P LDS. LDS 48->32KB: 5 blocks/CU (was 3).
// Max-free softmax (|S|<=6); per-lane l partials, reduced in epilogue.
__global__ __launch_bounds__(256) void attn_kernel(
    const u16* __restrict__ QKV, u16* __restrict__ Z)
{
    __shared__ u16 Ks[2][64 * 64];
    __shared__ u16 Vt[2][64 * 64];

    const int bh = blockIdx.y;
    const int b = bh >> 4, h = bh & 15;
    const int qt = (int)gridDim.x - 1 - (int)blockIdx.x;  // heavy tiles first
    const int tid = threadIdx.x;
    const int wave = tid >> 6, lane = tid & 63;
    const int l16 = lane & 15, lg = lane >> 4;

    const size_t baseQ = (size_t)b * 2048 * 3072 + (size_t)h * 64;
    const size_t baseK = baseQ + 1024;
    const size_t baseV = baseQ + 2048;

    const int q0w = qt * 128 + wave * 32;

    // Q fragments, pre-scaled by 1/sqrt(64)=0.125 (exact pow2)
    bf16x8 aq[2][2];
#pragma unroll
    for (int mq = 0; mq < 2; ++mq) {
        const u16* qp = QKV + baseQ + (size_t)(q0w + mq * 16 + l16) * 3072;
#pragma unroll
        for (int hf = 0; hf < 2; ++hf) {
            bf16x8 v = *(const bf16x8*)(qp + hf * 32 + lg * 8);
#pragma unroll
            for (int j = 0; j < 8; ++j) v[j] = (__bf16)((float)v[j] * 0.125f);
            aq[mq][hf] = v;
        }
    }

    f32x4 o[2][4];
    float lsum[2] = {0.f, 0.f};
#pragma unroll
    for (int mq = 0; mq < 2; ++mq)
#pragma unroll
        for (int i = 0; i < 4; ++i) o[mq][i] = (f32x4){0.f, 0.f, 0.f, 0.f};

    const int nch = 2 * qt + 2;

#define STAGE_K(BUF, KB)                                                      \
    {                                                                         \
        _Pragma("unroll")                                                     \
        for (int i = 0; i < 2; ++i) {                                         \
            int n = tid + i * 256;                                            \
            int r = n >> 3;                                                   \
            int lb = ((n & 7) * 16) ^ ((r & 7) << 4);                         \
            async_cp16(QKV + baseK + (size_t)((KB) + r) * 3072 + (lb >> 1),   \
                       Ks[BUF] + n * 8);                                      \
        }                                                                     \
    }
#define LOAD_V(KB, V0, V1)                                                    \
    {                                                                         \
        const u16* vp = QKV + baseV + (size_t)((KB) + lane) * 3072;           \
        V0 = *(const u16x8*)(vp + wave * 8);                                  \
        V1 = *(const u16x8*)(vp + wave * 8 + 32);                             \
    }
#define WRITE_V(BUF, V0, V1)                                                  \
    {                                                                         \
        _Pragma("unroll")                                                     \
        for (int j = 0; j < 8; ++j) {                                         \
            int d0 = wave * 8 + j;                                            \
            int by0 = (d0 * 128 + lane * 2) ^ ((d0 & 7) << 4);                \
            Vt[BUF][by0 >> 1] = V0[j];                                        \
            int d1 = d0 + 32;                                                 \
            int by1 = (d1 * 128 + lane * 2) ^ ((d1 & 7) << 4);                \
            Vt[BUF][by1 >> 1] = V1[j];                                        \
        }                                                                     \
    }

    // ---- prologue: stage chunk 0 into buffer 0 ----
    {
        STAGE_K(0, 0);
        u16x8 v0, v1;
        LOAD_V(0, v0, v1);
        WRITE_V(0, v0, v1);
    }
    __syncthreads();

    int cur = 0;
    for (int kc = 0; kc < nch; ++kc) {
        const int kbase = kc * 64;
        const int nxt = cur ^ 1;
        const bool more = (kc + 1 < nch);
        u16x8 nv0, nv1;
        if (more) {
            STAGE_K(nxt, kbase + 64);      // async global->LDS, drains at barrier
            LOAD_V(kbase + 64, nv0, nv1);  // global->reg, written post-compute
        }

        if (q0w + 31 >= kbase) {
            // ---- swapped QK^T: s[mq][t] = S^T[k-local=lg*4+r][q=l16] ----
            f32x4 s[2][4];
#pragma unroll
            for (int mq = 0; mq < 2; ++mq)
#pragma unroll
                for (int t = 0; t < 4; ++t) s[mq][t] = (f32x4){0.f, 0.f, 0.f, 0.f};
            __builtin_amdgcn_s_setprio(1);
#pragma unroll
            for (int t = 0; t < 4; ++t) {
                int row = t * 16 + l16;
                int swz = (row & 7) << 4;
                bf16x8 bk0 = *(const bf16x8*)(Ks[cur] + ((row * 128 + ((16 * lg) ^ swz)) >> 1));
                bf16x8 bk1 = *(const bf16x8*)(Ks[cur] + ((row * 128 + ((64 + 16 * lg) ^ swz)) >> 1));
#pragma unroll
                for (int mq = 0; mq < 2; ++mq) {
                    s[mq][t] = __builtin_amdgcn_mfma_f32_16x16x32_bf16(bk0, aq[mq][0], s[mq][t], 0, 0, 0);
                    s[mq][t] = __builtin_amdgcn_mfma_f32_16x16x32_bf16(bk1, aq[mq][1], s[mq][t], 0, 0, 0);
                }
            }
            __builtin_amdgcn_s_setprio(0);

            // ---- in-register max-free softmax + pack P A-frags ----
            const bool diag = (kbase + 63 > q0w);
            s16x4 pf[2][4];
#pragma unroll
            for (int mq = 0; mq < 2; ++mq) {
                const int ql = q0w + mq * 16 + l16;
#pragma unroll
                for (int t = 0; t < 4; ++t) {
#pragma unroll
                    for (int r = 0; r < 4; ++r) {
                        float x = s[mq][t][r];
                        if (diag && (kbase + t * 16 + lg * 4 + r > ql)) x = -1e30f;
                        float p = __expf(x);
                        lsum[mq] += p;
                        pf[mq][t][r] = (short)f2bf(p);
                    }
                }
            }

            // ---- PV: per k16-tile t, V B-frags via ds_read_b64 + 8 mfma16 ----
            __builtin_amdgcn_s_setprio(1);
#pragma unroll
            for (int t = 0; t < 4; ++t) {
                s16x4 vf[4];
#pragma unroll
                for (int ct = 0; ct < 4; ++ct) {
                    int d = ct * 16 + l16;
                    int byt = (d * 128 + (t * 16 + lg * 4) * 2) ^ ((d & 7) << 4);
                    vf[ct] = __builtin_bit_cast(s16x4, *(const u16x4*)(Vt[cur] + (byt >> 1)));
                }
#pragma unroll
                for (int mq = 0; mq < 2; ++mq)
#pragma unroll
                    for (int ct = 0; ct < 4; ++ct)
                        o[mq][ct] = __builtin_amdgcn_mfma_f32_16x16x16bf16_1k(
                            pf[mq][t], vf[ct], o[mq][ct], 0, 0, 0);
            }
            __builtin_amdgcn_s_setprio(0);
        }

        if (more) { WRITE_V(nxt, nv0, nv1); }  // vmcnt wait lands here (late)
        __syncthreads();                        // drains own async K + V writes
        cur = nxt;
    }

    // ---- epilogue: reduce l over lg-axis, transpose via shfl, store ----
#pragma unroll
    for (int mq = 0; mq < 2; ++mq) {
        float l = lsum[mq];
        l += __shfl_xor(l, 16);
        l += __shfl_xor(l, 32);      // l(q = q0w+mq*16+l16), replicated over lg
#pragma unroll
        for (int r = 0; r < 4; ++r) {
            float lq = __shfl(l, lg * 4 + r);   // sum for q-row lg*4+r
            float inv = 1.f / lq;
            size_t zr = ((size_t)b * 2048 + q0w + mq * 16 + lg * 4 + r) * 1024 + h * 64;
#pragma unroll
            for (int ct = 0; ct < 4; ++ct)
                Z[zr + ct * 16 + l16] = f2bf(o[mq][ct][r] * inv);
        }
    }
#undef STAGE_K
#undef LOAD_V
#undef WRITE_V
}

// ---------------------------------------------------------------------------
extern "C" void kernel_launch(void* const* d_in, const int* in_sizes, int n_in,
                              void* d_out, int out_size, void* d_ws, size_t ws_size,
                              hipStream_t stream)
{
    const float* X  = (const float*)d_in[0];
    const float* Wq = (const float*)d_in[1];
    const float* Wk = (const float*)d_in[2];
    const float* Wv = (const float*)d_in[3];
    const float* Wo = (const float*)d_in[4];
    const float* bo = (const float*)d_in[5];
    const float* W1 = (const float*)d_in[6];
    const float* b1 = (const float*)d_in[7];
    const float* W2 = (const float*)d_in[8];
    const float* b2 = (const float*)d_in[9];
    const float* g1 = (const float*)d_in[10];
    const float* s1 = (const float*)d_in[11];
    const float* g2 = (const float*)d_in[12];
    const float* s2 = (const float*)d_in[13];
    float* out = (float*)d_out;

    uint8_t* ws = (uint8_t*)d_ws;
    const size_t MB = 1024 * 1024;
    u16* Wqkvt = (u16*)(ws + 0 * MB);   // [3072][1024] bf16 (Q,K,V stacked)
    u16* Wot   = (u16*)(ws + 6 * MB);   // [1024][1024]
    u16* W1t   = (u16*)(ws + 8 * MB);   // [4096][1024]
    u16* W2t   = (u16*)(ws + 16 * MB);  // [1024][4096]
    u16* Yb    = (u16*)(ws + 24 * MB);  // [8192][1024] LN1 out
    u16* QKVb  = (u16*)(ws + 40 * MB);  // [8192][3072]
    u16* Zb    = (u16*)(ws + 24 * MB);  // reuse Yb (dead after QKV gemm)
    u16* Y2b   = (u16*)(ws + 40 * MB);  // reuse QKVb (dead after attention)
    u16* Hb    = (u16*)(ws + 56 * MB);  // [8192][4096]

    // 1) weight prep
    wtrans_kernel<<<dim3(32, 32), 256, 0, stream>>>(Wq, Wqkvt, 1024, 1024);
    wtrans_kernel<<<dim3(32, 32), 256, 0, stream>>>(Wk, Wqkvt + 1024 * 1024, 1024, 1024);
    wtrans_kernel<<<dim3(32, 32), 256, 0, stream>>>(Wv, Wqkvt + 2048 * 1024, 1024, 1024);
    wtrans_kernel<<<dim3(32, 32), 256, 0, stream>>>(Wo, Wot, 1024, 1024);
    wtrans_kernel<<<dim3(128, 32), 256, 0, stream>>>(W1, W1t, 1024, 4096);
    wtrans_kernel<<<dim3(32, 128), 256, 0, stream>>>(W2, W2t, 4096, 1024);

    // 2) LN1
    ln_kernel<<<8192, 256, 0, stream>>>(X, g1, s1, Yb);

    // 3) fused QKV projection (128^2 kernel; 1536 blocks, balanced)
    gemm_kernel<1, 0, 0, 0><<<dim3(24, 64), 256, 0, stream>>>(Yb, Wqkvt, nullptr, nullptr, QKVb, 8192, 3072, 1024);

    // 4) attention (swapped-QK^T, no P-LDS, 32KB LDS)
    attn_kernel<<<dim3(16, 64), 256, 0, stream>>>(QKVb, Zb);

    // 5) Wo projection + bo + shortcut X -> X1 (fp32 in d_out)
    gemm_kernel<0, 1, 1, 0><<<dim3(8, 64), 256, 0, stream>>>(Zb, Wot, bo, X, out, 8192, 1024, 1024);

    // 6) LN2
    ln_kernel<<<8192, 256, 0, stream>>>(out, g2, s2, Y2b);

    // 7) FFN up + gelu (8-phase 256^2; grid 16x32 = 512 % 8 == 0, balanced)
    gemm8p_kernel<1, 1, 1><<<dim3(16, 32), 512, 0, stream>>>(Y2b, W1t, b1, Hb, 8192, 4096, 1024);

    // 8) FFN down + b2 + residual (in-place on d_out, element-wise safe)
    gemm_kernel<0, 1, 1, 0><<<dim3(8, 64), 256, 0, stream>>>(Hb, W2t, b2, out, out, 8192, 1024, 4096);
}

// Round 11
// 437.504 us; speedup vs baseline: 1.1070x; 1.0867x over previous
//
#include <hip/hip_runtime.h>
#include <cstdint>
#include <cstddef>

#define DEV static __device__ __forceinline__

typedef __bf16 bf16x8 __attribute__((ext_vector_type(8)));
typedef float f32x4 __attribute__((ext_vector_type(4)));
typedef unsigned short u16x8 __attribute__((ext_vector_type(8)));
typedef unsigned short u16;

DEV u16 f2bf(float f) { __bf16 b = (__bf16)f; return __builtin_bit_cast(u16, b); }

DEV void async_cp16(const void* g, void* l) {
    __builtin_amdgcn_global_load_lds(
        (const __attribute__((address_space(1))) void*)g,
        (__attribute__((address_space(3))) void*)l, 16, 0, 0);
}

DEV void wait_vm6() { asm volatile("s_waitcnt vmcnt(6)" ::: "memory"); }
DEV void wait_vm4() { asm volatile("s_waitcnt vmcnt(4)" ::: "memory"); }
DEV void wait_vm0() { asm volatile("s_waitcnt vmcnt(0)" ::: "memory"); }

// gelu with module's custom 0.04715 constant; overflow-safe tanh
DEV float gelu_fn(float x) {
    const float c = 0.7978845608028654f; // sqrt(2/pi)
    float t = c * (x + 0.04715f * x * x * x);
    float e = __expf(2.f * t);
    float th = 1.f - 2.f / (e + 1.f); // tanh(t), safe at +-inf
    return 0.5f * x * (1.f + th);
}

// ------------- fused weight transpose+cast: all 6 weights, 1 launch --------
// W[K][N] f32 -> Wt[N][K] bf16, 32x32 tiles. Flat blockIdx segments:
// [0,4096): Wq/Wk/Wv/Wo (1024 tiles each); [4096,8192): W1; [8192,12288): W2.
__global__ __launch_bounds__(256) void wtrans_all_kernel(
    const float* __restrict__ Wq, const float* __restrict__ Wk,
    const float* __restrict__ Wv, const float* __restrict__ Wo,
    const float* __restrict__ W1, const float* __restrict__ W2,
    u16* __restrict__ Wqkvt, u16* __restrict__ Wot,
    u16* __restrict__ W1t, u16* __restrict__ W2t)
{
    const int bid = blockIdx.x;
    const float* W;
    u16* Wt;
    int K, N, nx, loc;
    if (bid < 4096) {
        loc = bid & 1023;
        const int wsel = bid >> 10;
        W = (wsel == 0) ? Wq : (wsel == 1) ? Wk : (wsel == 2) ? Wv : Wo;
        Wt = (wsel == 3) ? Wot : (Wqkvt + (size_t)wsel * 1024 * 1024);
        K = 1024; N = 1024; nx = 32;
    } else if (bid < 8192) {
        loc = bid - 4096; W = W1; Wt = W1t; K = 1024; N = 4096; nx = 128;
    } else {
        loc = bid - 8192; W = W2; Wt = W2t; K = 4096; N = 1024; nx = 32;
    }
    const int n0 = (loc % nx) * 32, k0 = (loc / nx) * 32;

    __shared__ float t[32][33];
    const int tx = threadIdx.x & 31, ty = threadIdx.x >> 5; // 32 x 8
#pragma unroll
    for (int i = 0; i < 4; ++i)
        t[ty + i * 8][tx] = W[(size_t)(k0 + ty + i * 8) * N + n0 + tx];
    __syncthreads();
#pragma unroll
    for (int i = 0; i < 4; ++i)
        Wt[(size_t)(n0 + ty + i * 8) * K + k0 + tx] = f2bf(t[tx][ty + i * 8]);
}

// ---------------- LayerNorm: f32 [rows][1024] -> bf16 ----------------------
__global__ __launch_bounds__(256) void ln_kernel(
    const float* __restrict__ X, const float* __restrict__ g,
    const float* __restrict__ sh, u16* __restrict__ Y)
{
    int row = blockIdx.x;
    const float4* xr = (const float4*)(X + (size_t)row * 1024);
    float4 x = xr[threadIdx.x];
    float s = x.x + x.y + x.z + x.w;
    float ss = x.x * x.x + x.y * x.y + x.z * x.z + x.w * x.w;
#pragma unroll
    for (int off = 32; off >= 1; off >>= 1) {
        s += __shfl_xor(s, off);
        ss += __shfl_xor(ss, off);
    }
    __shared__ float ps[4], pss[4];
    int wave = threadIdx.x >> 6, lane = threadIdx.x & 63;
    if (lane == 0) { ps[wave] = s; pss[wave] = ss; }
    __syncthreads();
    s = ps[0] + ps[1] + ps[2] + ps[3];
    ss = pss[0] + pss[1] + pss[2] + pss[3];
    float mean = s * (1.f / 1024.f);
    float var = ss * (1.f / 1024.f) - mean * mean;
    float rstd = rsqrtf(var + 1e-5f);
    int c = threadIdx.x * 4;
    ushort4 o;
    o.x = f2bf((x.x - mean) * rstd * g[c + 0] + sh[c + 0]);
    o.y = f2bf((x.y - mean) * rstd * g[c + 1] + sh[c + 1]);
    o.z = f2bf((x.z - mean) * rstd * g[c + 2] + sh[c + 2]);
    o.w = f2bf((x.w - mean) * rstd * g[c + 3] + sh[c + 3]);
    ((ushort4*)(Y + (size_t)row * 1024))[threadIdx.x] = o;
}

// ---------------- GEMM 128x128 (proven): C = A @ Bt^T ----------------------
// BK=32, 4 waves, 3-deep staging + counted vmcnt(4), single raw barrier per
// K-step (never drains the prefetch pipeline to 0 mid-loop).
template <int OUT_BF16, int HAS_BIAS, int HAS_RES, int ACT_GELU>
__global__ __launch_bounds__(256) void gemm_kernel(
    const u16* __restrict__ A, const u16* __restrict__ Bt,
    const float* __restrict__ bias, const float* __restrict__ res,
    void* __restrict__ Cout, int M, int N, int K)
{
    __shared__ u16 As[3][128 * 32];
    __shared__ u16 Bs[3][128 * 32];
    const int tid = threadIdx.x;
    const int lane = tid & 63, wave = tid >> 6;
    const int wm = wave >> 1, wn = wave & 1;
    const int l16 = lane & 15, lg = lane >> 4;
    const int rowBase = blockIdx.y * 128;
    const int colBase = blockIdx.x * 128;

    f32x4 acc[4][4];
#pragma unroll
    for (int m = 0; m < 4; ++m)
#pragma unroll
        for (int n = 0; n < 4; ++n) acc[m][n] = (f32x4){0.f, 0.f, 0.f, 0.f};

#define GSTAGE(SB, KT)                                                        \
    {                                                                         \
        _Pragma("unroll")                                                     \
        for (int i_ = 0; i_ < 2; ++i_) {                                      \
            int eo = tid * 8 + i_ * 2048;                                     \
            int r_ = eo >> 5, c_ = eo & 31;                                   \
            async_cp16(A + (size_t)(rowBase + r_) * K + (KT) + c_, As[SB] + eo); \
            async_cp16(Bt + (size_t)(colBase + r_) * K + (KT) + c_, Bs[SB] + eo); \
        }                                                                     \
    }

    const int nt = K >> 5;
    GSTAGE(0, 0);
    GSTAGE(1, 32);
    wait_vm4();
    __builtin_amdgcn_s_barrier();
    __builtin_amdgcn_sched_barrier(0);

    int cur = 0, stg = 2;
    for (int t = 0; t < nt; ++t) {
        const bool more = (t + 2 < nt);
        if (more) GSTAGE(stg, (t + 2) * 32);

        bf16x8 af[4], bfr[4];
#pragma unroll
        for (int m = 0; m < 4; ++m)
            af[m] = *(const bf16x8*)(As[cur] + (wm * 64 + m * 16 + l16) * 32 + lg * 8);
#pragma unroll
        for (int n = 0; n < 4; ++n)
            bfr[n] = *(const bf16x8*)(Bs[cur] + (wn * 64 + n * 16 + l16) * 32 + lg * 8);
#pragma unroll
        for (int m = 0; m < 4; ++m)
#pragma unroll
            for (int n = 0; n < 4; ++n)
                acc[m][n] = __builtin_amdgcn_mfma_f32_16x16x32_bf16(
                    af[m], bfr[n], acc[m][n], 0, 0, 0);

        if (more) wait_vm4(); else wait_vm0();
        __builtin_amdgcn_s_barrier();
        __builtin_amdgcn_sched_barrier(0);
        cur = (cur == 2) ? 0 : cur + 1;
        stg = (stg == 2) ? 0 : stg + 1;
    }
#undef GSTAGE

#pragma unroll
    for (int m = 0; m < 4; ++m) {
#pragma unroll
        for (int n = 0; n < 4; ++n) {
            int gr0 = rowBase + wm * 64 + m * 16 + lg * 4;
            int gc = colBase + wn * 64 + n * 16 + l16;
            float bv = HAS_BIAS ? bias[gc] : 0.f;
#pragma unroll
            for (int r = 0; r < 4; ++r) {
                float v = acc[m][n][r] + bv;
                if (ACT_GELU) v = gelu_fn(v);
                if (HAS_RES) v += res[(size_t)(gr0 + r) * N + gc];
                if (OUT_BF16)
                    ((u16*)Cout)[(size_t)(gr0 + r) * N + gc] = f2bf(v);
                else
                    ((float*)Cout)[(size_t)(gr0 + r) * N + gc] = v;
            }
        }
    }
}

// ---------------- GEMM 256x256, BK=64, 8 waves, 8-phase (R8-proven) --------
template <int OUT_BF16, int HAS_BIAS, int ACT_GELU>
__global__ __launch_bounds__(512, 2) void gemm8p_kernel(
    const u16* __restrict__ A, const u16* __restrict__ Bt,
    const float* __restrict__ bias, void* __restrict__ Cout,
    int M, int N, int K)
{
    __shared__ u16 As[2][256 * 64];
    __shared__ u16 Bs[2][256 * 64];
    const int tid = threadIdx.x;
    const int lane = tid & 63, wave = tid >> 6;
    const int wm = wave >> 2, wn = wave & 3;     // 2 x 4 wave grid
    const int l16 = lane & 15, lg = lane >> 4;

    const int gx = gridDim.x, gy = gridDim.y;
    const int nwg = gx * gy;
    const int orig = (int)blockIdx.y * gx + (int)blockIdx.x;
    const int work = (orig & 7) * (nwg >> 3) + (orig >> 3);
    const int colBase = (work / gy) * 256;
    const int rowBase = (work % gy) * 256;

    f32x4 acc[8][4];
#pragma unroll
    for (int m = 0; m < 8; ++m)
#pragma unroll
        for (int n = 0; n < 4; ++n) acc[m][n] = (f32x4){0.f, 0.f, 0.f, 0.f};

#define STRIP(SB, KT, S)                                                      \
    {                                                                         \
        int tl_ = tid & 255, hf_ = tid >> 8;                                  \
        int r_ = hf_ * 128 + (S) * 32 + (tl_ >> 3);                           \
        int gl_ = (tl_ & 7) ^ (r_ & 7);                                       \
        int dst_ = r_ * 64 + (tl_ & 7) * 8;                                   \
        async_cp16(A + (size_t)(rowBase + r_) * K + (KT) + gl_ * 8, As[SB] + dst_); \
        async_cp16(Bt + (size_t)(colBase + r_) * K + (KT) + gl_ * 8, Bs[SB] + dst_); \
    }
#define FRAG_OFF(row, G) ((row) * 64 + (((G) ^ ((row) & 7)) * 8))

#define PHASE(BUF, QUAD, LOADB, STAGE, WAITN)                                 \
    {                                                                         \
        __builtin_amdgcn_sched_barrier(0);                                    \
        if (LOADB) {                                                          \
            _Pragma("unroll")                                                 \
            for (int nf = 0; nf < 4; ++nf) {                                  \
                int row = wn * 64 + nf * 16 + l16;                            \
                _Pragma("unroll")                                             \
                for (int ks = 0; ks < 2; ++ks)                                \
                    bfr[nf][ks] = *(const bf16x8*)(Bs[BUF] + FRAG_OFF(row, lg + ks * 4)); \
            }                                                                 \
        }                                                                     \
        bf16x8 af[2][2];                                                      \
        _Pragma("unroll")                                                     \
        for (int mi = 0; mi < 2; ++mi) {                                      \
            int row = wm * 128 + (QUAD) * 32 + mi * 16 + l16;                 \
            _Pragma("unroll")                                                 \
            for (int ks = 0; ks < 2; ++ks)                                    \
                af[mi][ks] = *(const bf16x8*)(As[BUF] + FRAG_OFF(row, lg + ks * 4)); \
        }                                                                     \
        STAGE;                                                                \
        __builtin_amdgcn_sched_barrier(0);                                    \
        __builtin_amdgcn_s_barrier();                                         \
        __builtin_amdgcn_s_setprio(1);                                        \
        _Pragma("unroll")                                                     \
        for (int mi = 0; mi < 2; ++mi)                                        \
            _Pragma("unroll")                                                 \
            for (int nf = 0; nf < 4; ++nf)                                    \
                _Pragma("unroll")                                             \
                for (int ks = 0; ks < 2; ++ks)                                \
                    acc[(QUAD) * 2 + mi][nf] =                                \
                        __builtin_amdgcn_mfma_f32_16x16x32_bf16(              \
                            af[mi][ks], bfr[nf][ks], acc[(QUAD) * 2 + mi][nf], 0, 0, 0); \
        __builtin_amdgcn_s_setprio(0);                                        \
        __builtin_amdgcn_sched_barrier(0);                                    \
        WAITN;                                                                \
        __builtin_amdgcn_s_barrier();                                         \
    }

    const int nt = K >> 6;
    const int half = nt >> 1;

    STRIP(0, 0, 0); STRIP(0, 0, 1); STRIP(0, 0, 2); STRIP(0, 0, 3);
    STRIP(1, 64, 0); STRIP(1, 64, 1); STRIP(1, 64, 2);
    wait_vm6();
    __builtin_amdgcn_s_barrier();
    __builtin_amdgcn_sched_barrier(0);

    for (int it = 0; it < half; ++it) {
        const int kt1 = (it * 2 + 1) << 6;
        const int kt2 = (it * 2 + 2) << 6;
        const int kt3 = (it * 2 + 3) << 6;
        const bool more = (it + 1 < half);
        bf16x8 bfr[4][2];
        PHASE(0, 0, 1, STRIP(1, kt1, 3), ((void)0));
        PHASE(0, 1, 0, if (more) STRIP(0, kt2, 0), ((void)0));
        PHASE(0, 2, 0, if (more) STRIP(0, kt2, 1), ((void)0));
        PHASE(0, 3, 0, if (more) STRIP(0, kt2, 2),
              if (more) wait_vm6(); else wait_vm0());
        PHASE(1, 0, 1, if (more) STRIP(0, kt2, 3), ((void)0));
        PHASE(1, 1, 0, if (more) STRIP(1, kt3, 0), ((void)0));
        PHASE(1, 2, 0, if (more) STRIP(1, kt3, 1), ((void)0));
        PHASE(1, 3, 0, if (more) STRIP(1, kt3, 2),
              if (more) wait_vm6(); else wait_vm0());
    }
#undef STRIP
#undef FRAG_OFF
#undef PHASE

#pragma unroll
    for (int mf = 0; mf < 8; ++mf) {
#pragma unroll
        for (int nf = 0; nf < 4; ++nf) {
            int gr0 = rowBase + wm * 128 + mf * 16 + lg * 4;
            int gc = colBase + wn * 64 + nf * 16 + l16;
            float bv = HAS_BIAS ? bias[gc] : 0.f;
#pragma unroll
            for (int r = 0; r < 4; ++r) {
                float v = acc[mf][nf][r] + bv;
                if (ACT_GELU) v = gelu_fn(v);
                if (OUT_BF16)
                    ((u16*)Cout)[(size_t)(gr0 + r) * N + gc] = f2bf(v);
                else
                    ((float*)Cout)[(size_t)(gr0 + r) * N + gc] = v;
            }
        }
    }
}

// ---------------- causal flash attention (v9: QBLK=256, 8 waves) -----------
// QKV fused: bf16 [8192][3072]. Z: bf16 [8192][1024].
// 8 waves/block, wave owns 32 q rows (QBLK=256 total), KVBLK=64. Same
// R6-proven per-wave inner pipeline (QK^T -> max-free softmax -> P LDS -> PV,
// double-buffered staging, one __syncthreads per chunk), but 8 waves share
// each staged K/V chunk: staging work per unit compute halves, and chunk
// iterations per bh drop 272 -> 144. Grid 8x64 = 512 blocks, 2/CU resident.
__global__ __launch_bounds__(512) void attn_kernel(
    const u16* __restrict__ QKV, u16* __restrict__ Z)
{
    __shared__ u16 Ks[2][64 * 64];
    __shared__ u16 Vt[2][64 * 64];
    __shared__ u16 Pl[8][32 * 64];

    const int bh = blockIdx.y;
    const int b = bh >> 4, h = bh & 15;
    const int qt = (int)gridDim.x - 1 - (int)blockIdx.x;  // heavy tiles first
    const int tid = threadIdx.x;
    const int wave = tid >> 6, lane = tid & 63;
    const int l16 = lane & 15, lg = lane >> 4;

    const size_t baseQ = (size_t)b * 2048 * 3072 + (size_t)h * 64;
    const size_t baseK = baseQ + 1024;
    const size_t baseV = baseQ + 2048;

    const int q0w = qt * 256 + wave * 32;

    // Q fragments, pre-scaled by 1/sqrt(64)=0.125 (exact pow2)
    bf16x8 aq[2][2];
#pragma unroll
    for (int mq = 0; mq < 2; ++mq) {
        const u16* qp = QKV + baseQ + (size_t)(q0w + mq * 16 + l16) * 3072;
#pragma unroll
        for (int hf = 0; hf < 2; ++hf) {
            bf16x8 v = *(const bf16x8*)(qp + hf * 32 + lg * 8);
#pragma unroll
            for (int j = 0; j < 8; ++j) v[j] = (__bf16)((float)v[j] * 0.125f);
            aq[mq][hf] = v;
        }
    }

    f32x4 o[2][4];
    float lrow[2][4];
#pragma unroll
    for (int mq = 0; mq < 2; ++mq)
#pragma unroll
        for (int i = 0; i < 4; ++i) {
            o[mq][i] = (f32x4){0.f, 0.f, 0.f, 0.f};
            lrow[mq][i] = 0.f;
        }

    const int nch = 4 * qt + 4;

    // 512 threads: one cp16 each covers the 64x64 K tile (xor-swizzled rows)
#define STAGE_K(BUF, KB)                                                      \
    {                                                                         \
        int n = tid;                                                          \
        int r = n >> 3;                                                       \
        int lb = ((n & 7) * 16) ^ ((r & 7) << 4);                             \
        async_cp16(QKV + baseK + (size_t)((KB) + r) * 3072 + (lb >> 1),       \
                   Ks[BUF] + n * 8);                                          \
    }
    // wave w owns d rows w*8..w*8+7; lane = k (64 lanes)
#define LOAD_V(KB, V0)                                                        \
    {                                                                         \
        const u16* vp = QKV + baseV + (size_t)((KB) + lane) * 3072;           \
        V0 = *(const u16x8*)(vp + wave * 8);                                  \
    }
#define WRITE_V(BUF, V0)                                                      \
    {                                                                         \
        _Pragma("unroll")                                                     \
        for (int j = 0; j < 8; ++j) {                                         \
            int d = wave * 8 + j;                                             \
            int byt = (d * 128 + lane * 2) ^ ((d & 7) << 4);                  \
            Vt[BUF][byt >> 1] = V0[j];                                        \
        }                                                                     \
    }
#define SOFTMAX_BODY(DIAG)                                                    \
    _Pragma("unroll")                                                         \
    for (int mq = 0; mq < 2; ++mq) {                                          \
        _Pragma("unroll")                                                     \
        for (int r = 0; r < 4; ++r) {                                         \
            float sv0 = s[mq][0][r];                                          \
            float sv1 = s[mq][1][r];                                          \
            float sv2 = s[mq][2][r];                                          \
            float sv3 = s[mq][3][r];                                          \
            if (DIAG) {                                                       \
                const int q = q0w + mq * 16 + lg * 4 + r;                     \
                if (kbase + 0 + l16 > q)  sv0 = -1e30f;                       \
                if (kbase + 16 + l16 > q) sv1 = -1e30f;                       \
                if (kbase + 32 + l16 > q) sv2 = -1e30f;                       \
                if (kbase + 48 + l16 > q) sv3 = -1e30f;                       \
            }                                                                 \
            float p0 = __expf(sv0), p1 = __expf(sv1);                         \
            float p2 = __expf(sv2), p3 = __expf(sv3);                         \
            lrow[mq][r] += (p0 + p1) + (p2 + p3);                             \
            int rowm = mq * 16 + lg * 4 + r;                                  \
            int rb = rowm * 128, swz = (rowm & 7) << 4;                       \
            Pl[wave][(rb + ((0  + 2 * l16) ^ swz)) >> 1] = f2bf(p0);          \
            Pl[wave][(rb + ((32 + 2 * l16) ^ swz)) >> 1] = f2bf(p1);          \
            Pl[wave][(rb + ((64 + 2 * l16) ^ swz)) >> 1] = f2bf(p2);          \
            Pl[wave][(rb + ((96 + 2 * l16) ^ swz)) >> 1] = f2bf(p3);          \
        }                                                                     \
    }

    // ---- prologue: stage chunk 0 into buffer 0 ----
    {
        STAGE_K(0, 0);
        u16x8 v0;
        LOAD_V(0, v0);
        WRITE_V(0, v0);
    }
    __syncthreads();

    int cur = 0;
    for (int kc = 0; kc < nch; ++kc) {
        const int kbase = kc * 64;
        const int nxt = cur ^ 1;
        const bool more = (kc + 1 < nch);
        u16x8 nv0;
        if (more) {
            STAGE_K(nxt, kbase + 64);      // async global->LDS, drains at barrier
            LOAD_V(kbase + 64, nv0);       // global->reg, written post-compute
        }

        if (q0w + 31 >= kbase) {
            // ---- QK^T: S[32 q][64 k] ----
            f32x4 s[2][4];
#pragma unroll
            for (int mq = 0; mq < 2; ++mq)
#pragma unroll
                for (int t = 0; t < 4; ++t) s[mq][t] = (f32x4){0.f, 0.f, 0.f, 0.f};
            __builtin_amdgcn_s_setprio(1);
#pragma unroll
            for (int t = 0; t < 4; ++t) {
                int row = t * 16 + l16;
                int swz = (row & 7) << 4;
                bf16x8 bk0 = *(const bf16x8*)(Ks[cur] + ((row * 128 + ((16 * lg) ^ swz)) >> 1));
                bf16x8 bk1 = *(const bf16x8*)(Ks[cur] + ((row * 128 + ((64 + 16 * lg) ^ swz)) >> 1));
#pragma unroll
                for (int mq = 0; mq < 2; ++mq) {
                    s[mq][t] = __builtin_amdgcn_mfma_f32_16x16x32_bf16(aq[mq][0], bk0, s[mq][t], 0, 0, 0);
                    s[mq][t] = __builtin_amdgcn_mfma_f32_16x16x32_bf16(aq[mq][1], bk1, s[mq][t], 0, 0, 0);
                }
            }
            __builtin_amdgcn_s_setprio(0);

            // ---- max-free softmax + P -> LDS ----
            const bool diag = (kbase + 63 > q0w);
            if (diag) { SOFTMAX_BODY(1) } else { SOFTMAX_BODY(0) }

            // ---- PV: O[32 q][64 d] += P @ V ----
            bf16x8 bv[2][4];
#pragma unroll
            for (int kst = 0; kst < 2; ++kst)
#pragma unroll
                for (int ct = 0; ct < 4; ++ct) {
                    int d = ct * 16 + l16;
                    bv[kst][ct] = *(const bf16x8*)(Vt[cur] + ((d * 128 + ((64 * kst + 16 * lg) ^ ((d & 7) << 4))) >> 1));
                }
            __builtin_amdgcn_s_setprio(1);
#pragma unroll
            for (int mq = 0; mq < 2; ++mq) {
                int rowm = mq * 16 + l16;
                int swz = (rowm & 7) << 4;
                bf16x8 ap0 = *(const bf16x8*)(&Pl[wave][(rowm * 128 + ((16 * lg) ^ swz)) >> 1]);
                bf16x8 ap1 = *(const bf16x8*)(&Pl[wave][(rowm * 128 + ((64 + 16 * lg) ^ swz)) >> 1]);
#pragma unroll
                for (int ct = 0; ct < 4; ++ct) {
                    o[mq][ct] = __builtin_amdgcn_mfma_f32_16x16x32_bf16(ap0, bv[0][ct], o[mq][ct], 0, 0, 0);
                    o[mq][ct] = __builtin_amdgcn_mfma_f32_16x16x32_bf16(ap1, bv[1][ct], o[mq][ct], 0, 0, 0);
                }
            }
            __builtin_amdgcn_s_setprio(0);
        }

        if (more) { WRITE_V(nxt, nv0); }   // vmcnt wait lands here (late)
        __syncthreads();                    // drains own async K + V writes
        cur = nxt;
    }

    // ---- epilogue: reduce l across the 16 k-lanes, normalize, store ----
#pragma unroll
    for (int mq = 0; mq < 2; ++mq)
#pragma unroll
        for (int r = 0; r < 4; ++r) {
            float l = lrow[mq][r];
            l += __shfl_xor(l, 1);
            l += __shfl_xor(l, 2);
            l += __shfl_xor(l, 4);
            l += __shfl_xor(l, 8);
            float inv = 1.f / l;
            size_t zr = ((size_t)b * 2048 + q0w + mq * 16 + lg * 4 + r) * 1024 + h * 64;
#pragma unroll
            for (int ct = 0; ct < 4; ++ct)
                Z[zr + ct * 16 + l16] = f2bf(o[mq][ct][r] * inv);
        }
#undef STAGE_K
#undef LOAD_V
#undef WRITE_V
#undef SOFTMAX_BODY
}

// ---------------------------------------------------------------------------
extern "C" void kernel_launch(void* const* d_in, const int* in_sizes, int n_in,
                              void* d_out, int out_size, void* d_ws, size_t ws_size,
                              hipStream_t stream)
{
    const float* X  = (const float*)d_in[0];
    const float* Wq = (const float*)d_in[1];
    const float* Wk = (const float*)d_in[2];
    const float* Wv = (const float*)d_in[3];
    const float* Wo = (const float*)d_in[4];
    const float* bo = (const float*)d_in[5];
    const float* W1 = (const float*)d_in[6];
    const float* b1 = (const float*)d_in[7];
    const float* W2 = (const float*)d_in[8];
    const float* b2 = (const float*)d_in[9];
    const float* g1 = (const float*)d_in[10];
    const float* s1 = (const float*)d_in[11];
    const float* g2 = (const float*)d_in[12];
    const float* s2 = (const float*)d_in[13];
    float* out = (float*)d_out;

    uint8_t* ws = (uint8_t*)d_ws;
    const size_t MB = 1024 * 1024;
    u16* Wqkvt = (u16*)(ws + 0 * MB);   // [3072][1024] bf16 (Q,K,V stacked)
    u16* Wot   = (u16*)(ws + 6 * MB);   // [1024][1024]
    u16* W1t   = (u16*)(ws + 8 * MB);   // [4096][1024]
    u16* W2t   = (u16*)(ws + 16 * MB);  // [1024][4096]
    u16* Yb    = (u16*)(ws + 24 * MB);  // [8192][1024] LN1 out
    u16* QKVb  = (u16*)(ws + 40 * MB);  // [8192][3072]
    u16* Zb    = (u16*)(ws + 24 * MB);  // reuse Yb (dead after QKV gemm)
    u16* Y2b   = (u16*)(ws + 40 * MB);  // reuse QKVb (dead after attention)
    u16* Hb    = (u16*)(ws + 56 * MB);  // [8192][4096]

    // 1) weight prep (single fused launch, 12288 tiles)
    wtrans_all_kernel<<<12288, 256, 0, stream>>>(Wq, Wk, Wv, Wo, W1, W2,
                                                 Wqkvt, Wot, W1t, W2t);

    // 2) LN1
    ln_kernel<<<8192, 256, 0, stream>>>(X, g1, s1, Yb);

    // 3) fused QKV projection (128^2 kernel; 1536 blocks, balanced)
    gemm_kernel<1, 0, 0, 0><<<dim3(24, 64), 256, 0, stream>>>(Yb, Wqkvt, nullptr, nullptr, QKVb, 8192, 3072, 1024);

    // 4) attention (QBLK=256, 8 waves, grid 8x64)
    attn_kernel<<<dim3(8, 64), 512, 0, stream>>>(QKVb, Zb);

    // 5) Wo projection + bo + shortcut X -> X1 (fp32 in d_out)
    gemm_kernel<0, 1, 1, 0><<<dim3(8, 64), 256, 0, stream>>>(Zb, Wot, bo, X, out, 8192, 1024, 1024);

    // 6) LN2
    ln_kernel<<<8192, 256, 0, stream>>>(out, g2, s2, Y2b);

    // 7) FFN up + gelu (8-phase 256^2; grid 16x32 = 512 % 8 == 0, balanced)
    gemm8p_kernel<1, 1, 1><<<dim3(16, 32), 512, 0, stream>>>(Y2b, W1t, b1, Hb, 8192, 4096, 1024);

    // 8) FFN down + b2 + residual (in-place on d_out, element-wise safe)
    gemm_kernel<0, 1, 1, 0><<<dim3(8, 64), 256, 0, stream>>>(Hb, W2t, b2, out, out, 8192, 1024, 4096);
}

// Round 12
// 408.435 us; speedup vs baseline: 1.1858x; 1.0712x over previous
//
#include <hip/hip_runtime.h>
#include <cstdint>
#include <cstddef>

#define DEV static __device__ __forceinline__

typedef __bf16 bf16x8 __attribute__((ext_vector_type(8)));
typedef float f32x4 __attribute__((ext_vector_type(4)));
typedef unsigned short u16x8 __attribute__((ext_vector_type(8)));
typedef unsigned short u16;

DEV u16 f2bf(float f) { __bf16 b = (__bf16)f; return __builtin_bit_cast(u16, b); }

DEV void async_cp16(const void* g, void* l) {
    __builtin_amdgcn_global_load_lds(
        (const __attribute__((address_space(1))) void*)g,
        (__attribute__((address_space(3))) void*)l, 16, 0, 0);
}

DEV void wait_vm6() { asm volatile("s_waitcnt vmcnt(6)" ::: "memory"); }
DEV void wait_vm4() { asm volatile("s_waitcnt vmcnt(4)" ::: "memory"); }
DEV void wait_vm0() { asm volatile("s_waitcnt vmcnt(0)" ::: "memory"); }

// gelu with module's custom 0.04715 constant; overflow-safe tanh
DEV float gelu_fn(float x) {
    const float c = 0.7978845608028654f; // sqrt(2/pi)
    float t = c * (x + 0.04715f * x * x * x);
    float e = __expf(2.f * t);
    float th = 1.f - 2.f / (e + 1.f); // tanh(t), safe at +-inf
    return 0.5f * x * (1.f + th);
}

// ------------- fused weight transpose+cast: all 6 weights, 1 launch --------
// W[K][N] f32 -> Wt[N][K] bf16, 32x32 tiles. Flat blockIdx segments:
// [0,4096): Wq/Wk/Wv/Wo (1024 tiles each); [4096,8192): W1; [8192,12288): W2.
__global__ __launch_bounds__(256) void wtrans_all_kernel(
    const float* __restrict__ Wq, const float* __restrict__ Wk,
    const float* __restrict__ Wv, const float* __restrict__ Wo,
    const float* __restrict__ W1, const float* __restrict__ W2,
    u16* __restrict__ Wqkvt, u16* __restrict__ Wot,
    u16* __restrict__ W1t, u16* __restrict__ W2t)
{
    const int bid = blockIdx.x;
    const float* W;
    u16* Wt;
    int K, N, nx, loc;
    if (bid < 4096) {
        loc = bid & 1023;
        const int wsel = bid >> 10;
        W = (wsel == 0) ? Wq : (wsel == 1) ? Wk : (wsel == 2) ? Wv : Wo;
        Wt = (wsel == 3) ? Wot : (Wqkvt + (size_t)wsel * 1024 * 1024);
        K = 1024; N = 1024; nx = 32;
    } else if (bid < 8192) {
        loc = bid - 4096; W = W1; Wt = W1t; K = 1024; N = 4096; nx = 128;
    } else {
        loc = bid - 8192; W = W2; Wt = W2t; K = 4096; N = 1024; nx = 32;
    }
    const int n0 = (loc % nx) * 32, k0 = (loc / nx) * 32;

    __shared__ float t[32][33];
    const int tx = threadIdx.x & 31, ty = threadIdx.x >> 5; // 32 x 8
#pragma unroll
    for (int i = 0; i < 4; ++i)
        t[ty + i * 8][tx] = W[(size_t)(k0 + ty + i * 8) * N + n0 + tx];
    __syncthreads();
#pragma unroll
    for (int i = 0; i < 4; ++i)
        Wt[(size_t)(n0 + ty + i * 8) * K + k0 + tx] = f2bf(t[tx][ty + i * 8]);
}

// ---------------- LayerNorm: f32 [rows][1024] -> bf16 ----------------------
__global__ __launch_bounds__(256) void ln_kernel(
    const float* __restrict__ X, const float* __restrict__ g,
    const float* __restrict__ sh, u16* __restrict__ Y)
{
    int row = blockIdx.x;
    const float4* xr = (const float4*)(X + (size_t)row * 1024);
    float4 x = xr[threadIdx.x];
    float s = x.x + x.y + x.z + x.w;
    float ss = x.x * x.x + x.y * x.y + x.z * x.z + x.w * x.w;
#pragma unroll
    for (int off = 32; off >= 1; off >>= 1) {
        s += __shfl_xor(s, off);
        ss += __shfl_xor(ss, off);
    }
    __shared__ float ps[4], pss[4];
    int wave = threadIdx.x >> 6, lane = threadIdx.x & 63;
    if (lane == 0) { ps[wave] = s; pss[wave] = ss; }
    __syncthreads();
    s = ps[0] + ps[1] + ps[2] + ps[3];
    ss = pss[0] + pss[1] + pss[2] + pss[3];
    float mean = s * (1.f / 1024.f);
    float var = ss * (1.f / 1024.f) - mean * mean;
    float rstd = rsqrtf(var + 1e-5f);
    int c = threadIdx.x * 4;
    ushort4 o;
    o.x = f2bf((x.x - mean) * rstd * g[c + 0] + sh[c + 0]);
    o.y = f2bf((x.y - mean) * rstd * g[c + 1] + sh[c + 1]);
    o.z = f2bf((x.z - mean) * rstd * g[c + 2] + sh[c + 2]);
    o.w = f2bf((x.w - mean) * rstd * g[c + 3] + sh[c + 3]);
    ((ushort4*)(Y + (size_t)row * 1024))[threadIdx.x] = o;
}

// ---------------- GEMM 128x128 (proven): C = A @ Bt^T ----------------------
// BK=32, 4 waves, 3-deep staging + counted vmcnt(4), single raw barrier per
// K-step (never drains the prefetch pipeline to 0 mid-loop).
template <int OUT_BF16, int HAS_BIAS, int HAS_RES, int ACT_GELU>
__global__ __launch_bounds__(256) void gemm_kernel(
    const u16* __restrict__ A, const u16* __restrict__ Bt,
    const float* __restrict__ bias, const float* __restrict__ res,
    void* __restrict__ Cout, int M, int N, int K)
{
    __shared__ u16 As[3][128 * 32];
    __shared__ u16 Bs[3][128 * 32];
    const int tid = threadIdx.x;
    const int lane = tid & 63, wave = tid >> 6;
    const int wm = wave >> 1, wn = wave & 1;
    const int l16 = lane & 15, lg = lane >> 4;
    const int rowBase = blockIdx.y * 128;
    const int colBase = blockIdx.x * 128;

    f32x4 acc[4][4];
#pragma unroll
    for (int m = 0; m < 4; ++m)
#pragma unroll
        for (int n = 0; n < 4; ++n) acc[m][n] = (f32x4){0.f, 0.f, 0.f, 0.f};

#define GSTAGE(SB, KT)                                                        \
    {                                                                         \
        _Pragma("unroll")                                                     \
        for (int i_ = 0; i_ < 2; ++i_) {                                      \
            int eo = tid * 8 + i_ * 2048;                                     \
            int r_ = eo >> 5, c_ = eo & 31;                                   \
            async_cp16(A + (size_t)(rowBase + r_) * K + (KT) + c_, As[SB] + eo); \
            async_cp16(Bt + (size_t)(colBase + r_) * K + (KT) + c_, Bs[SB] + eo); \
        }                                                                     \
    }

    const int nt = K >> 5;
    GSTAGE(0, 0);
    GSTAGE(1, 32);
    wait_vm4();
    __builtin_amdgcn_s_barrier();
    __builtin_amdgcn_sched_barrier(0);

    int cur = 0, stg = 2;
    for (int t = 0; t < nt; ++t) {
        const bool more = (t + 2 < nt);
        if (more) GSTAGE(stg, (t + 2) * 32);

        bf16x8 af[4], bfr[4];
#pragma unroll
        for (int m = 0; m < 4; ++m)
            af[m] = *(const bf16x8*)(As[cur] + (wm * 64 + m * 16 + l16) * 32 + lg * 8);
#pragma unroll
        for (int n = 0; n < 4; ++n)
            bfr[n] = *(const bf16x8*)(Bs[cur] + (wn * 64 + n * 16 + l16) * 32 + lg * 8);
#pragma unroll
        for (int m = 0; m < 4; ++m)
#pragma unroll
            for (int n = 0; n < 4; ++n)
                acc[m][n] = __builtin_amdgcn_mfma_f32_16x16x32_bf16(
                    af[m], bfr[n], acc[m][n], 0, 0, 0);

        if (more) wait_vm4(); else wait_vm0();
        __builtin_amdgcn_s_barrier();
        __builtin_amdgcn_sched_barrier(0);
        cur = (cur == 2) ? 0 : cur + 1;
        stg = (stg == 2) ? 0 : stg + 1;
    }
#undef GSTAGE

#pragma unroll
    for (int m = 0; m < 4; ++m) {
#pragma unroll
        for (int n = 0; n < 4; ++n) {
            int gr0 = rowBase + wm * 64 + m * 16 + lg * 4;
            int gc = colBase + wn * 64 + n * 16 + l16;
            float bv = HAS_BIAS ? bias[gc] : 0.f;
#pragma unroll
            for (int r = 0; r < 4; ++r) {
                float v = acc[m][n][r] + bv;
                if (ACT_GELU) v = gelu_fn(v);
                if (HAS_RES) v += res[(size_t)(gr0 + r) * N + gc];
                if (OUT_BF16)
                    ((u16*)Cout)[(size_t)(gr0 + r) * N + gc] = f2bf(v);
                else
                    ((float*)Cout)[(size_t)(gr0 + r) * N + gc] = v;
            }
        }
    }
}

// ---------------- GEMM 256x256, BK=64, 8 waves, 8-phase (R8-proven) --------
template <int OUT_BF16, int HAS_BIAS, int ACT_GELU>
__global__ __launch_bounds__(512, 2) void gemm8p_kernel(
    const u16* __restrict__ A, const u16* __restrict__ Bt,
    const float* __restrict__ bias, void* __restrict__ Cout,
    int M, int N, int K)
{
    __shared__ u16 As[2][256 * 64];
    __shared__ u16 Bs[2][256 * 64];
    const int tid = threadIdx.x;
    const int lane = tid & 63, wave = tid >> 6;
    const int wm = wave >> 2, wn = wave & 3;     // 2 x 4 wave grid
    const int l16 = lane & 15, lg = lane >> 4;

    const int gx = gridDim.x, gy = gridDim.y;
    const int nwg = gx * gy;
    const int orig = (int)blockIdx.y * gx + (int)blockIdx.x;
    const int work = (orig & 7) * (nwg >> 3) + (orig >> 3);
    const int colBase = (work / gy) * 256;
    const int rowBase = (work % gy) * 256;

    f32x4 acc[8][4];
#pragma unroll
    for (int m = 0; m < 8; ++m)
#pragma unroll
        for (int n = 0; n < 4; ++n) acc[m][n] = (f32x4){0.f, 0.f, 0.f, 0.f};

#define STRIP(SB, KT, S)                                                      \
    {                                                                         \
        int tl_ = tid & 255, hf_ = tid >> 8;                                  \
        int r_ = hf_ * 128 + (S) * 32 + (tl_ >> 3);                           \
        int gl_ = (tl_ & 7) ^ (r_ & 7);                                       \
        int dst_ = r_ * 64 + (tl_ & 7) * 8;                                   \
        async_cp16(A + (size_t)(rowBase + r_) * K + (KT) + gl_ * 8, As[SB] + dst_); \
        async_cp16(Bt + (size_t)(colBase + r_) * K + (KT) + gl_ * 8, Bs[SB] + dst_); \
    }
#define FRAG_OFF(row, G) ((row) * 64 + (((G) ^ ((row) & 7)) * 8))

#define PHASE(BUF, QUAD, LOADB, STAGE, WAITN)                                 \
    {                                                                         \
        __builtin_amdgcn_sched_barrier(0);                                    \
        if (LOADB) {                                                          \
            _Pragma("unroll")                                                 \
            for (int nf = 0; nf < 4; ++nf) {                                  \
                int row = wn * 64 + nf * 16 + l16;                            \
                _Pragma("unroll")                                             \
                for (int ks = 0; ks < 2; ++ks)                                \
                    bfr[nf][ks] = *(const bf16x8*)(Bs[BUF] + FRAG_OFF(row, lg + ks * 4)); \
            }                                                                 \
        }                                                                     \
        bf16x8 af[2][2];                                                      \
        _Pragma("unroll")                                                     \
        for (int mi = 0; mi < 2; ++mi) {                                      \
            int row = wm * 128 + (QUAD) * 32 + mi * 16 + l16;                 \
            _Pragma("unroll")                                                 \
            for (int ks = 0; ks < 2; ++ks)                                    \
                af[mi][ks] = *(const bf16x8*)(As[BUF] + FRAG_OFF(row, lg + ks * 4)); \
        }                                                                     \
        STAGE;                                                                \
        __builtin_amdgcn_sched_barrier(0);                                    \
        __builtin_amdgcn_s_barrier();                                         \
        __builtin_amdgcn_s_setprio(1);                                        \
        _Pragma("unroll")                                                     \
        for (int mi = 0; mi < 2; ++mi)                                        \
            _Pragma("unroll")                                                 \
            for (int nf = 0; nf < 4; ++nf)                                    \
                _Pragma("unroll")                                             \
                for (int ks = 0; ks < 2; ++ks)                                \
                    acc[(QUAD) * 2 + mi][nf] =                                \
                        __builtin_amdgcn_mfma_f32_16x16x32_bf16(              \
                            af[mi][ks], bfr[nf][ks], acc[(QUAD) * 2 + mi][nf], 0, 0, 0); \
        __builtin_amdgcn_s_setprio(0);                                        \
        __builtin_amdgcn_sched_barrier(0);                                    \
        WAITN;                                                                \
        __builtin_amdgcn_s_barrier();                                         \
    }

    const int nt = K >> 6;
    const int half = nt >> 1;

    STRIP(0, 0, 0); STRIP(0, 0, 1); STRIP(0, 0, 2); STRIP(0, 0, 3);
    STRIP(1, 64, 0); STRIP(1, 64, 1); STRIP(1, 64, 2);
    wait_vm6();
    __builtin_amdgcn_s_barrier();
    __builtin_amdgcn_sched_barrier(0);

    for (int it = 0; it < half; ++it) {
        const int kt1 = (it * 2 + 1) << 6;
        const int kt2 = (it * 2 + 2) << 6;
        const int kt3 = (it * 2 + 3) << 6;
        const bool more = (it + 1 < half);
        bf16x8 bfr[4][2];
        PHASE(0, 0, 1, STRIP(1, kt1, 3), ((void)0));
        PHASE(0, 1, 0, if (more) STRIP(0, kt2, 0), ((void)0));
        PHASE(0, 2, 0, if (more) STRIP(0, kt2, 1), ((void)0));
        PHASE(0, 3, 0, if (more) STRIP(0, kt2, 2),
              if (more) wait_vm6(); else wait_vm0());
        PHASE(1, 0, 1, if (more) STRIP(0, kt2, 3), ((void)0));
        PHASE(1, 1, 0, if (more) STRIP(1, kt3, 0), ((void)0));
        PHASE(1, 2, 0, if (more) STRIP(1, kt3, 1), ((void)0));
        PHASE(1, 3, 0, if (more) STRIP(1, kt3, 2),
              if (more) wait_vm6(); else wait_vm0());
    }
#undef STRIP
#undef FRAG_OFF
#undef PHASE

#pragma unroll
    for (int mf = 0; mf < 8; ++mf) {
#pragma unroll
        for (int nf = 0; nf < 4; ++nf) {
            int gr0 = rowBase + wm * 128 + mf * 16 + lg * 4;
            int gc = colBase + wn * 64 + nf * 16 + l16;
            float bv = HAS_BIAS ? bias[gc] : 0.f;
#pragma unroll
            for (int r = 0; r < 4; ++r) {
                float v = acc[mf][nf][r] + bv;
                if (ACT_GELU) v = gelu_fn(v);
                if (OUT_BF16)
                    ((u16*)Cout)[(size_t)(gr0 + r) * N + gc] = f2bf(v);
                else
                    ((float*)Cout)[(size_t)(gr0 + r) * N + gc] = v;
            }
        }
    }
}

// ---------------- causal flash attention (v10: balanced grid) --------------
// QKV fused: bf16 [8192][3072]. Z: bf16 [8192][1024].
// 8 waves/block, QBLK=256, KVBLK=64; R6/R11-proven per-wave pipeline.
// Grid (64 bh, 8 g) with qt = (g<4)?(7-g):(g-4): stride-256 co-resident
// block pairs (n, n+256) have complementary qt (sum=7) -> every CU hosts a
// heavy+light pair = uniform 36 chunk-units (was: same-qt pairs, 64-unit
// worst CUs setting the runtime).
__global__ __launch_bounds__(512) void attn_kernel(
    const u16* __restrict__ QKV, u16* __restrict__ Z)
{
    __shared__ u16 Ks[2][64 * 64];
    __shared__ u16 Vt[2][64 * 64];
    __shared__ u16 Pl[8][32 * 64];

    const int bh = blockIdx.x;               // 0..63
    const int b = bh >> 4, h = bh & 15;
    const int g = blockIdx.y;                // 0..7
    const int qt = (g < 4) ? (7 - g) : (g - 4);  // complementary at stride 256
    const int tid = threadIdx.x;
    const int wave = tid >> 6, lane = tid & 63;
    const int l16 = lane & 15, lg = lane >> 4;

    const size_t baseQ = (size_t)b * 2048 * 3072 + (size_t)h * 64;
    const size_t baseK = baseQ + 1024;
    const size_t baseV = baseQ + 2048;

    const int q0w = qt * 256 + wave * 32;

    // Q fragments, pre-scaled by 1/sqrt(64)=0.125 (exact pow2)
    bf16x8 aq[2][2];
#pragma unroll
    for (int mq = 0; mq < 2; ++mq) {
        const u16* qp = QKV + baseQ + (size_t)(q0w + mq * 16 + l16) * 3072;
#pragma unroll
        for (int hf = 0; hf < 2; ++hf) {
            bf16x8 v = *(const bf16x8*)(qp + hf * 32 + lg * 8);
#pragma unroll
            for (int j = 0; j < 8; ++j) v[j] = (__bf16)((float)v[j] * 0.125f);
            aq[mq][hf] = v;
        }
    }

    f32x4 o[2][4];
    float lrow[2][4];
#pragma unroll
    for (int mq = 0; mq < 2; ++mq)
#pragma unroll
        for (int i = 0; i < 4; ++i) {
            o[mq][i] = (f32x4){0.f, 0.f, 0.f, 0.f};
            lrow[mq][i] = 0.f;
        }

    const int nch = 4 * qt + 4;

    // 512 threads: one cp16 each covers the 64x64 K tile (xor-swizzled rows)
#define STAGE_K(BUF, KB)                                                      \
    {                                                                         \
        int n = tid;                                                          \
        int r = n >> 3;                                                       \
        int lb = ((n & 7) * 16) ^ ((r & 7) << 4);                             \
        async_cp16(QKV + baseK + (size_t)((KB) + r) * 3072 + (lb >> 1),       \
                   Ks[BUF] + n * 8);                                          \
    }
    // wave w owns d rows w*8..w*8+7; lane = k (64 lanes)
#define LOAD_V(KB, V0)                                                        \
    {                                                                         \
        const u16* vp = QKV + baseV + (size_t)((KB) + lane) * 3072;           \
        V0 = *(const u16x8*)(vp + wave * 8);                                  \
    }
#define WRITE_V(BUF, V0)                                                      \
    {                                                                         \
        _Pragma("unroll")                                                     \
        for (int j = 0; j < 8; ++j) {                                         \
            int d = wave * 8 + j;                                             \
            int byt = (d * 128 + lane * 2) ^ ((d & 7) << 4);                  \
            Vt[BUF][byt >> 1] = V0[j];                                        \
        }                                                                     \
    }
#define SOFTMAX_BODY(DIAG)                                                    \
    _Pragma("unroll")                                                         \
    for (int mq = 0; mq < 2; ++mq) {                                          \
        _Pragma("unroll")                                                     \
        for (int r = 0; r < 4; ++r) {                                         \
            float sv0 = s[mq][0][r];                                          \
            float sv1 = s[mq][1][r];                                          \
            float sv2 = s[mq][2][r];                                          \
            float sv3 = s[mq][3][r];                                          \
            if (DIAG) {                                                       \
                const int q = q0w + mq * 16 + lg * 4 + r;                     \
                if (kbase + 0 + l16 > q)  sv0 = -1e30f;                       \
                if (kbase + 16 + l16 > q) sv1 = -1e30f;                       \
                if (kbase + 32 + l16 > q) sv2 = -1e30f;                       \
                if (kbase + 48 + l16 > q) sv3 = -1e30f;                       \
            }                                                                 \
            float p0 = __expf(sv0), p1 = __expf(sv1);                         \
            float p2 = __expf(sv2), p3 = __expf(sv3);                         \
            lrow[mq][r] += (p0 + p1) + (p2 + p3);                             \
            int rowm = mq * 16 + lg * 4 + r;                                  \
            int rb = rowm * 128, swz = (rowm & 7) << 4;                       \
            Pl[wave][(rb + ((0  + 2 * l16) ^ swz)) >> 1] = f2bf(p0);          \
            Pl[wave][(rb + ((32 + 2 * l16) ^ swz)) >> 1] = f2bf(p1);          \
            Pl[wave][(rb + ((64 + 2 * l16) ^ swz)) >> 1] = f2bf(p2);          \
            Pl[wave][(rb + ((96 + 2 * l16) ^ swz)) >> 1] = f2bf(p3);          \
        }                                                                     \
    }

    // ---- prologue: stage chunk 0 into buffer 0 ----
    {
        STAGE_K(0, 0);
        u16x8 v0;
        LOAD_V(0, v0);
        WRITE_V(0, v0);
    }
    __syncthreads();

    int cur = 0;
    for (int kc = 0; kc < nch; ++kc) {
        const int kbase = kc * 64;
        const int nxt = cur ^ 1;
        const bool more = (kc + 1 < nch);
        u16x8 nv0;
        if (more) {
            STAGE_K(nxt, kbase + 64);      // async global->LDS, drains at barrier
            LOAD_V(kbase + 64, nv0);       // global->reg, written post-compute
        }

        if (q0w + 31 >= kbase) {
            // ---- QK^T: S[32 q][64 k] ----
            f32x4 s[2][4];
#pragma unroll
            for (int mq = 0; mq < 2; ++mq)
#pragma unroll
                for (int t = 0; t < 4; ++t) s[mq][t] = (f32x4){0.f, 0.f, 0.f, 0.f};
            __builtin_amdgcn_s_setprio(1);
#pragma unroll
            for (int t = 0; t < 4; ++t) {
                int row = t * 16 + l16;
                int swz = (row & 7) << 4;
                bf16x8 bk0 = *(const bf16x8*)(Ks[cur] + ((row * 128 + ((16 * lg) ^ swz)) >> 1));
                bf16x8 bk1 = *(const bf16x8*)(Ks[cur] + ((row * 128 + ((64 + 16 * lg) ^ swz)) >> 1));
#pragma unroll
                for (int mq = 0; mq < 2; ++mq) {
                    s[mq][t] = __builtin_amdgcn_mfma_f32_16x16x32_bf16(aq[mq][0], bk0, s[mq][t], 0, 0, 0);
                    s[mq][t] = __builtin_amdgcn_mfma_f32_16x16x32_bf16(aq[mq][1], bk1, s[mq][t], 0, 0, 0);
                }
            }
            __builtin_amdgcn_s_setprio(0);

            // ---- max-free softmax + P -> LDS ----
            const bool diag = (kbase + 63 > q0w);
            if (diag) { SOFTMAX_BODY(1) } else { SOFTMAX_BODY(0) }

            // ---- PV: O[32 q][64 d] += P @ V ----
            bf16x8 bv[2][4];
#pragma unroll
            for (int kst = 0; kst < 2; ++kst)
#pragma unroll
                for (int ct = 0; ct < 4; ++ct) {
                    int d = ct * 16 + l16;
                    bv[kst][ct] = *(const bf16x8*)(Vt[cur] + ((d * 128 + ((64 * kst + 16 * lg) ^ ((d & 7) << 4))) >> 1));
                }
            __builtin_amdgcn_s_setprio(1);
#pragma unroll
            for (int mq = 0; mq < 2; ++mq) {
                int rowm = mq * 16 + l16;
                int swz = (rowm & 7) << 4;
                bf16x8 ap0 = *(const bf16x8*)(&Pl[wave][(rowm * 128 + ((16 * lg) ^ swz)) >> 1]);
                bf16x8 ap1 = *(const bf16x8*)(&Pl[wave][(rowm * 128 + ((64 + 16 * lg) ^ swz)) >> 1]);
#pragma unroll
                for (int ct = 0; ct < 4; ++ct) {
                    o[mq][ct] = __builtin_amdgcn_mfma_f32_16x16x32_bf16(ap0, bv[0][ct], o[mq][ct], 0, 0, 0);
                    o[mq][ct] = __builtin_amdgcn_mfma_f32_16x16x32_bf16(ap1, bv[1][ct], o[mq][ct], 0, 0, 0);
                }
            }
            __builtin_amdgcn_s_setprio(0);
        }

        if (more) { WRITE_V(nxt, nv0); }   // vmcnt wait lands here (late)
        __syncthreads();                    // drains own async K + V writes
        cur = nxt;
    }

    // ---- epilogue: reduce l across the 16 k-lanes, normalize, store ----
#pragma unroll
    for (int mq = 0; mq < 2; ++mq)
#pragma unroll
        for (int r = 0; r < 4; ++r) {
            float l = lrow[mq][r];
            l += __shfl_xor(l, 1);
            l += __shfl_xor(l, 2);
            l += __shfl_xor(l, 4);
            l += __shfl_xor(l, 8);
            float inv = 1.f / l;
            size_t zr = ((size_t)b * 2048 + q0w + mq * 16 + lg * 4 + r) * 1024 + h * 64;
#pragma unroll
            for (int ct = 0; ct < 4; ++ct)
                Z[zr + ct * 16 + l16] = f2bf(o[mq][ct][r] * inv);
        }
#undef STAGE_K
#undef LOAD_V
#undef WRITE_V
#undef SOFTMAX_BODY
}

// ---------------------------------------------------------------------------
extern "C" void kernel_launch(void* const* d_in, const int* in_sizes, int n_in,
                              void* d_out, int out_size, void* d_ws, size_t ws_size,
                              hipStream_t stream)
{
    const float* X  = (const float*)d_in[0];
    const float* Wq = (const float*)d_in[1];
    const float* Wk = (const float*)d_in[2];
    const float* Wv = (const float*)d_in[3];
    const float* Wo = (const float*)d_in[4];
    const float* bo = (const float*)d_in[5];
    const float* W1 = (const float*)d_in[6];
    const float* b1 = (const float*)d_in[7];
    const float* W2 = (const float*)d_in[8];
    const float* b2 = (const float*)d_in[9];
    const float* g1 = (const float*)d_in[10];
    const float* s1 = (const float*)d_in[11];
    const float* g2 = (const float*)d_in[12];
    const float* s2 = (const float*)d_in[13];
    float* out = (float*)d_out;

    uint8_t* ws = (uint8_t*)d_ws;
    const size_t MB = 1024 * 1024;
    u16* Wqkvt = (u16*)(ws + 0 * MB);   // [3072][1024] bf16 (Q,K,V stacked)
    u16* Wot   = (u16*)(ws + 6 * MB);   // [1024][1024]
    u16* W1t   = (u16*)(ws + 8 * MB);   // [4096][1024]
    u16* W2t   = (u16*)(ws + 16 * MB);  // [1024][4096]
    u16* Yb    = (u16*)(ws + 24 * MB);  // [8192][1024] LN1 out
    u16* QKVb  = (u16*)(ws + 40 * MB);  // [8192][3072]
    u16* Zb    = (u16*)(ws + 24 * MB);  // reuse Yb (dead after QKV gemm)
    u16* Y2b   = (u16*)(ws + 40 * MB);  // reuse QKVb (dead after attention)
    u16* Hb    = (u16*)(ws + 56 * MB);  // [8192][4096]

    // 1) weight prep (single fused launch, 12288 tiles)
    wtrans_all_kernel<<<12288, 256, 0, stream>>>(Wq, Wk, Wv, Wo, W1, W2,
                                                 Wqkvt, Wot, W1t, W2t);

    // 2) LN1
    ln_kernel<<<8192, 256, 0, stream>>>(X, g1, s1, Yb);

    // 3) fused QKV projection (128^2 kernel; 1536 blocks, balanced)
    gemm_kernel<1, 0, 0, 0><<<dim3(24, 64), 256, 0, stream>>>(Yb, Wqkvt, nullptr, nullptr, QKVb, 8192, 3072, 1024);

    // 4) attention (QBLK=256, 8 waves, CU-balanced grid 64x8)
    attn_kernel<<<dim3(64, 8), 512, 0, stream>>>(QKVb, Zb);

    // 5) Wo projection + bo + shortcut X -> X1 (fp32 in d_out)
    gemm_kernel<0, 1, 1, 0><<<dim3(8, 64), 256, 0, stream>>>(Zb, Wot, bo, X, out, 8192, 1024, 1024);

    // 6) LN2
    ln_kernel<<<8192, 256, 0, stream>>>(out, g2, s2, Y2b);

    // 7) FFN up + gelu (8-phase 256^2; grid 16x32 = 512 % 8 == 0, balanced)
    gemm8p_kernel<1, 1, 1><<<dim3(16, 32), 512, 0, stream>>>(Y2b, W1t, b1, Hb, 8192, 4096, 1024);

    // 8) FFN down + b2 + residual (in-place on d_out, element-wise safe)
    gemm_kernel<0, 1, 1, 0><<<dim3(8, 64), 256, 0, stream>>>(Hb, W2t, b2, out, out, 8192, 1024, 4096);
}